// Round 11
// baseline (730.083 us; speedup 1.0000x reference)
//
#include <hip/hip_runtime.h>
#include <hip/hip_bf16.h>
#include <cstdint>
#include <cstddef>

#define N_NODES 50000
#define N_EDGES 1600000
#define N_FEAT  512
#define N_HID   256
#define N_CLS   64
#define K_HOPS  10
#define NPAD    50016                       // plane rows incl. dummy zero row
#define DUMMY   N_NODES                     // pad edges point here (zeroed)
#define P16(d) (((d) + 15) & ~15)
#define STAGE_CAP 256                       // csr entries staged in LDS per wave
#define HOP_GRID 3125                       // 16 nodes/block x 3125 = 50000
#define NPS 6250                            // nodes per XCD slice (scatter)

typedef __attribute__((ext_vector_type(4))) float f32x4;
typedef __attribute__((ext_vector_type(4))) int   i32x4;
typedef __attribute__((ext_vector_type(8))) short s16x8;

__device__ __forceinline__ ushort f2bf(float f) {
    uint32_t u = __float_as_uint(f);
    uint32_t r = (u + 0x7FFFu + ((u >> 16) & 1u)) >> 16;
    return (ushort)r;
}

// packed fp32x2 -> bf16x2, single VALU op. NON-volatile: pure, schedulable.
__device__ __forceinline__ uint32_t cvtpk(float a, float b) {
    uint32_t r;
    asm("v_cvt_pk_bf16_f32 %0, %1, %2" : "=v"(r) : "v"(a), "v"(b));
    return r;
}

// ------- prepass: X (and W1) fp32 -> bf16, pure streaming, full occupancy ------
__global__ void xb_k(const float* __restrict__ X, const float* __restrict__ W1,
                     ushort* __restrict__ Xb, ushort* __restrict__ W1b) {
    const size_t NX = (size_t)N_NODES * N_FEAT;   // 25,600,000
    const size_t NW = (size_t)N_HID * N_FEAT;     // 131,072
    size_t i = ((size_t)blockIdx.x * 256 + threadIdx.x) * 8;
    if (i < NX) {
        const f32x4 a = *reinterpret_cast<const f32x4*>(X + i);
        const f32x4 b = *reinterpret_cast<const f32x4*>(X + i + 4);
        uint4 o;
        o.x = cvtpk(a[0], a[1]); o.y = cvtpk(a[2], a[3]);
        o.z = cvtpk(b[0], b[1]); o.w = cvtpk(b[2], b[3]);
        *reinterpret_cast<uint4*>(Xb + i) = o;
    } else {
        size_t j = i - NX;
        if (j < NW) {
            const f32x4 a = *reinterpret_cast<const f32x4*>(W1 + j);
            const f32x4 b = *reinterpret_cast<const f32x4*>(W1 + j + 4);
            uint4 o;
            o.x = cvtpk(a[0], a[1]); o.y = cvtpk(a[2], a[3]);
            o.z = cvtpk(b[0], b[1]); o.w = cvtpk(b[2], b[3]);
            *reinterpret_cast<uint4*>(W1b + j) = o;
        }
    }
}

// ---- GEMM1: H = relu(Xb @ W1b^T), bf16 inputs, pure-copy staging --------------
__launch_bounds__(256)
__global__ void gemm1_k(const ushort* __restrict__ Xb, const ushort* __restrict__ W1b,
                        ushort* __restrict__ H) {
    __shared__ ushort sA[128 * 64];
    __shared__ ushort sB[128 * 64];
    const int m0 = blockIdx.x * 128;
    const int n0 = blockIdx.y * 128;
    const int t = threadIdx.x;
    const int wid = t >> 6, lane = t & 63;
    const int wr = wid >> 1, wc = wid & 1;
    const int lo = lane & 15, hi = lane >> 4;

    f32x4 acc[4][4] = {};

    for (int kt = 0; kt < N_FEAT; kt += 64) {
        #pragma unroll
        for (int p = 0; p < 4; ++p) {
            int idx = p * 256 + t;
            int row = idx >> 3, g = idx & 7;
            int grow = m0 + row; if (grow > N_NODES - 1) grow = N_NODES - 1;
            uint4 v = *reinterpret_cast<const uint4*>(Xb + (size_t)grow * N_FEAT + kt + g * 8);
            *reinterpret_cast<uint4*>(&sA[row * 64 + ((g ^ (row & 7)) << 3)]) = v;
        }
        #pragma unroll
        for (int p = 0; p < 4; ++p) {
            int idx = p * 256 + t;
            int row = idx >> 3, g = idx & 7;
            uint4 v = *reinterpret_cast<const uint4*>(W1b + (size_t)(n0 + row) * N_FEAT + kt + g * 8);
            *reinterpret_cast<uint4*>(&sB[row * 64 + ((g ^ (row & 7)) << 3)]) = v;
        }
        __syncthreads();
        #pragma unroll
        for (int kk = 0; kk < 2; ++kk) {
            const int g = kk * 4 + hi;
            s16x8 a[4], b[4];
            #pragma unroll
            for (int i = 0; i < 4; ++i) {
                int row = wr * 64 + i * 16 + lo;
                a[i] = *reinterpret_cast<const s16x8*>(&sA[row * 64 + ((g ^ (row & 7)) << 3)]);
            }
            #pragma unroll
            for (int j = 0; j < 4; ++j) {
                int row = wc * 64 + j * 16 + lo;
                b[j] = *reinterpret_cast<const s16x8*>(&sB[row * 64 + ((g ^ (row & 7)) << 3)]);
            }
            #pragma unroll
            for (int i = 0; i < 4; ++i)
                #pragma unroll
                for (int j = 0; j < 4; ++j)
                    acc[i][j] = __builtin_amdgcn_mfma_f32_16x16x32_bf16(a[i], b[j], acc[i][j], 0, 0, 0);
        }
        __syncthreads();
    }
    #pragma unroll
    for (int i = 0; i < 4; ++i) {
        int rbase = m0 + wr * 64 + i * 16 + hi * 4;
        #pragma unroll
        for (int j = 0; j < 4; ++j) {
            int col = n0 + wc * 64 + j * 16 + lo;
            #pragma unroll
            for (int r = 0; r < 4; ++r) {
                int row = rbase + r;
                if (row < N_NODES) {
                    float v = acc[i][j][r];
                    H[(size_t)row * N_HID + col] = f2bf(fmaxf(v, 0.0f));
                }
            }
        }
    }
}

// ---- GEMM2: h~0 = dinv * (H @ W2^T), row-major [NPAD][64] ---------------------
__launch_bounds__(256)
__global__ void gemm2_k(const ushort* __restrict__ H, const float* __restrict__ W2,
                        const float* __restrict__ dinv, float* __restrict__ out) {
    __shared__ ushort sA[128 * 64];
    __shared__ ushort sB[64 * 64];
    const int m0 = blockIdx.x * 128;
    const int t = threadIdx.x;
    const int wid = t >> 6, lane = t & 63;
    const int lo = lane & 15, hi = lane >> 4;

    f32x4 acc[2][4] = {};

    for (int kt = 0; kt < N_HID; kt += 64) {
        #pragma unroll
        for (int p = 0; p < 4; ++p) {
            int idx = p * 256 + t;
            int row = idx >> 3, g = idx & 7;
            int grow = m0 + row; if (grow > N_NODES - 1) grow = N_NODES - 1;
            uint4 v = *reinterpret_cast<const uint4*>(H + (size_t)grow * N_HID + kt + g * 8);
            *reinterpret_cast<uint4*>(&sA[row * 64 + ((g ^ (row & 7)) << 3)]) = v;
        }
        #pragma unroll
        for (int p = 0; p < 4; ++p) {
            int idx = p * 256 + t;
            int row = idx >> 4, f4 = idx & 15;
            const float4 v = *reinterpret_cast<const float4*>(W2 + (size_t)row * N_HID + kt + f4 * 4);
            uint2 h; h.x = cvtpk(v.x, v.y); h.y = cvtpk(v.z, v.w);
            int g = f4 >> 1;
            int off = row * 64 + ((g ^ (row & 7)) << 3) + ((f4 & 1) << 2);
            *reinterpret_cast<uint2*>(&sB[off]) = h;
        }
        __syncthreads();
        #pragma unroll
        for (int kk = 0; kk < 2; ++kk) {
            const int g = kk * 4 + hi;
            s16x8 a[2], b[4];
            #pragma unroll
            for (int i = 0; i < 2; ++i) {
                int row = wid * 32 + i * 16 + lo;
                a[i] = *reinterpret_cast<const s16x8*>(&sA[row * 64 + ((g ^ (row & 7)) << 3)]);
            }
            #pragma unroll
            for (int j = 0; j < 4; ++j) {
                int row = j * 16 + lo;
                b[j] = *reinterpret_cast<const s16x8*>(&sB[row * 64 + ((g ^ (row & 7)) << 3)]);
            }
            #pragma unroll
            for (int i = 0; i < 2; ++i)
                #pragma unroll
                for (int j = 0; j < 4; ++j)
                    acc[i][j] = __builtin_amdgcn_mfma_f32_16x16x32_bf16(a[i], b[j], acc[i][j], 0, 0, 0);
        }
        __syncthreads();
    }
    // row-major store scaled by dinv: out[row][j*16+lo]
    #pragma unroll
    for (int i = 0; i < 2; ++i) {
        int rbase = m0 + wid * 32 + i * 16 + hi * 4;
        #pragma unroll
        for (int r = 0; r < 4; ++r) {
            int row = rbase + r;
            if (row < N_NODES) {
                const float dv = dinv[row];
                #pragma unroll
                for (int j = 0; j < 4; ++j)
                    out[(size_t)row * 64 + j * 16 + lo] = acc[i][j][r] * dv;
            }
        }
    }
}

// ------- degree: unsliced, 4 edges/thread, NONTEMPORAL edge stream -------------
__global__ void deg_k(const int* __restrict__ dst, int* __restrict__ deg) {
    int e = (blockIdx.x * 256 + threadIdx.x) * 4;
    if (e + 3 < N_EDGES) {
        const i32x4 d = __builtin_nontemporal_load(
            reinterpret_cast<const i32x4*>(dst + e));
        atomicAdd(&deg[d[0]], 1);
        atomicAdd(&deg[d[1]], 1);
        atomicAdd(&deg[d[2]], 1);
        atomicAdd(&deg[d[3]], 1);
    } else {
        for (int k = 0; k < 4 && e + k < N_EDGES; ++k)
            atomicAdd(&deg[dst[e + k]], 1);
    }
}

__global__ void dinv_k(const int* __restrict__ deg, float* __restrict__ dinv,
                       float* __restrict__ rd) {
    int n = blockIdx.x * 256 + threadIdx.x;
    if (n < N_NODES) {
        float dp1 = (float)deg[n] + 1.0f;     // +1 self loop
        dinv[n] = rsqrtf(dp1);
        rd[n]   = sqrtf(dp1);
    }
}

// ------------- CSR build: scan over PADDED degrees + scatter + padfill ---------
__device__ __forceinline__ int wave_incl_scan(int v, int lane) {
    #pragma unroll
    for (int d = 1; d < 64; d <<= 1) {
        int u = __shfl_up(v, d, 64);
        if (lane >= d) v += u;
    }
    return v;
}

__global__ void scan_p1(const int* __restrict__ cnt, int* __restrict__ partial) {
    int i = blockIdx.x * 256 + threadIdx.x;
    int v = (i < N_NODES) ? P16(cnt[i]) : 0;
    #pragma unroll
    for (int d = 32; d; d >>= 1) v += __shfl_xor(v, d, 64);
    __shared__ int wt[4];
    int wid = threadIdx.x >> 6, lane = threadIdx.x & 63;
    if (lane == 0) wt[wid] = v;
    __syncthreads();
    if (threadIdx.x == 0) partial[blockIdx.x] = wt[0] + wt[1] + wt[2] + wt[3];
}

__global__ void scan_p2(const int* __restrict__ partial, int* __restrict__ chunkoff,
                        int* __restrict__ row_ptr) {
    int t = threadIdx.x;
    int v = (t < 196) ? partial[t] : 0;
    int lane = t & 63, wid = t >> 6;
    int incl = wave_incl_scan(v, lane);
    __shared__ int wt[4];
    if (lane == 63) wt[wid] = incl;
    __syncthreads();
    int woff = 0;
    for (int w = 0; w < wid; ++w) woff += wt[w];
    int excl = incl - v + woff;
    if (t < 196) chunkoff[t] = excl;
    if (t == 0) row_ptr[N_NODES] = wt[0] + wt[1] + wt[2] + wt[3];  // padded total
}

__global__ void scan_p3(const int* __restrict__ cnt, const int* __restrict__ chunkoff,
                        int* __restrict__ row_ptr) {
    int i = blockIdx.x * 256 + threadIdx.x;
    int v = (i < N_NODES) ? P16(cnt[i]) : 0;
    int lane = threadIdx.x & 63, wid = threadIdx.x >> 6;
    int incl = wave_incl_scan(v, lane);
    __shared__ int wt[4];
    if (lane == 63) wt[wid] = incl;
    __syncthreads();
    int woff = 0;
    for (int w = 0; w < wid; ++w) woff += wt[w];
    int excl = incl - v + woff;
    if (i < N_NODES) row_ptr[i] = chunkoff[blockIdx.x] + excl;
}

// ---- scatter: 8-way XCD-sliced, NONTEMPORAL edge stream -----------------------
// r10 diagnosis: WRITE 64.8MB for 9.6MB payload was streaming src/dst THROUGH
// L2 evicting dirty csr lines repeatedly. nt loads don't allocate -> dirty
// slice-local csr lines survive to one final writeback.
__global__ void scatter_k(const int* __restrict__ src, const int* __restrict__ dst,
                          const int* __restrict__ row_ptr,
                          int* __restrict__ cursor, int* __restrict__ csr) {
    const int slice = blockIdx.x & 7;
    const int lo = slice * NPS;
    int e = ((blockIdx.x >> 3) * 256 + threadIdx.x) * 4;
    if (e + 3 < N_EDGES) {
        const i32x4 d4 = __builtin_nontemporal_load(
            reinterpret_cast<const i32x4*>(dst + e));
        const i32x4 s4 = __builtin_nontemporal_load(
            reinterpret_cast<const i32x4*>(src + e));
        #pragma unroll
        for (int k = 0; k < 4; ++k) {
            const int d = d4[k];
            if ((unsigned)(d - lo) < (unsigned)NPS) {
                int pos = atomicAdd(&cursor[d], 1);
                csr[row_ptr[d] + pos] = s4[k];
            }
        }
    } else {
        for (int k = 0; k < 4 && e + k < N_EDGES; ++k) {
            int d = dst[e + k];
            if ((unsigned)(d - lo) < (unsigned)NPS) {
                int pos = atomicAdd(&cursor[d], 1);
                csr[row_ptr[d] + pos] = src[e + k];
            }
        }
    }
}

__global__ void padfill_k(const int* __restrict__ deg, const int* __restrict__ row_ptr,
                          int* __restrict__ csr) {
    int n = blockIdx.x * 256 + threadIdx.x;
    if (n >= N_NODES) return;
    int d = deg[n];
    int base = row_ptr[n] + d;
    int pad = P16(d) - d;
    for (int i = 0; i < pad; ++i) csr[base + i] = DUMMY;
}

// zero the dummy row (64 floats) in the 3 state buffers
__global__ void zdum_k(float* __restrict__ b0, float* __restrict__ b1,
                       float* __restrict__ b2) {
    int t = threadIdx.x;
    if (t >= 192) return;
    float* b = (t < 64) ? b0 : (t < 128) ? b1 : b2;
    int w = t & 63;
    b[(size_t)DUMMY * 64 + w] = 0.0f;
}

// ---------------- one APPNP hop: single-pass full-row, 8-deep MLP --------------
// p~'[d] = 0.9*dinv[d]^2*(sum_{s in N(d)} p~[s] + p~[d]) + 0.1*h~0[d]
// Planes row-major [NPAD][64] fp32. Wave = 4 edge-slots x 16 lanes x f32x4.
// Main loop = 32 entries/iter: 8 independent gathers in flight per lane; tail
// is exactly one 16-entry batch (P16 segments). 4 nodes/wave, csr segment
// LDS-staged with 4 parallel nt loads; pads hit the zeroed DUMMY row.
__launch_bounds__(256)
__global__ void hop_k(const float* __restrict__ prev, const float* __restrict__ h0,
                      float* __restrict__ next, const int* __restrict__ csr,
                      const int* __restrict__ row_ptr, const float* __restrict__ dinv) {
    __shared__ int scsr[4][STAGE_CAP];
    const int bid = blockIdx.x;
    const int wid = threadIdx.x >> 6;
    const int lane = threadIdx.x & 63;
    const int nb = bid * 16 + wid * 4;             // first of this wave's 4 nodes
    const int slot = lane >> 4;                    // edge slot 0..3
    const int cq = (lane & 15) << 2;               // float offset in 64-f row

    const int b0 = __builtin_amdgcn_readfirstlane(row_ptr[nb]);
    const int e0 = __builtin_amdgcn_readfirstlane(row_ptr[nb + 1]);
    const int e1 = __builtin_amdgcn_readfirstlane(row_ptr[nb + 2]);
    const int e2 = __builtin_amdgcn_readfirstlane(row_ptr[nb + 3]);
    const int e3 = __builtin_amdgcn_readfirstlane(row_ptr[nb + 4]);
    const int tot = e3 - b0;

    int* sw = scsr[wid];
    #pragma unroll
    for (int k = 0; k < 4; ++k) {
        int off = k * 64 + lane;
        if (off < tot && off < STAGE_CAP)
            sw[off] = __builtin_nontemporal_load(csr + b0 + off);
    }

    f32x4 a0 = {0.f,0.f,0.f,0.f}, a1 = a0, a2 = a0, a3 = a0;

#define NODE_LOOP(Bg, Eg, ACC)                                                   \
    {                                                                            \
        int ib = (Bg);                                                           \
        for (; ib + 32 <= (Eg); ib += 32) {                                      \
            int s[8];                                                            \
            if (ib + 32 - b0 <= STAGE_CAP) {                                     \
                int base = ib - b0 + slot;                                       \
                _Pragma("unroll")                                                \
                for (int k = 0; k < 8; ++k) s[k] = sw[base + 4 * k];             \
            } else {                                                             \
                _Pragma("unroll")                                                \
                for (int k = 0; k < 8; ++k)                                      \
                    s[k] = __builtin_nontemporal_load(csr + ib + slot + 4 * k);  \
            }                                                                    \
            f32x4 p[8];                                                          \
            _Pragma("unroll")                                                    \
            for (int k = 0; k < 8; ++k)                                          \
                p[k] = *reinterpret_cast<const f32x4*>(prev + (size_t)s[k] * 64 + cq); \
            _Pragma("unroll")                                                    \
            for (int k = 0; k < 8; ++k) {                                        \
                ACC[0] += p[k][0]; ACC[1] += p[k][1];                            \
                ACC[2] += p[k][2]; ACC[3] += p[k][3];                            \
            }                                                                    \
        }                                                                        \
        if (ib < (Eg)) {                                                         \
            int s[4];                                                            \
            if (ib + 16 - b0 <= STAGE_CAP) {                                     \
                int base = ib - b0 + slot;                                       \
                _Pragma("unroll")                                                \
                for (int k = 0; k < 4; ++k) s[k] = sw[base + 4 * k];             \
            } else {                                                             \
                _Pragma("unroll")                                                \
                for (int k = 0; k < 4; ++k)                                      \
                    s[k] = __builtin_nontemporal_load(csr + ib + slot + 4 * k);  \
            }                                                                    \
            f32x4 p[4];                                                          \
            _Pragma("unroll")                                                    \
            for (int k = 0; k < 4; ++k)                                          \
                p[k] = *reinterpret_cast<const f32x4*>(prev + (size_t)s[k] * 64 + cq); \
            _Pragma("unroll")                                                    \
            for (int k = 0; k < 4; ++k) {                                        \
                ACC[0] += p[k][0]; ACC[1] += p[k][1];                            \
                ACC[2] += p[k][2]; ACC[3] += p[k][3];                            \
            }                                                                    \
        }                                                                        \
    }

    NODE_LOOP(b0, e0, a0)
    NODE_LOOP(e0, e1, a1)
    NODE_LOOP(e1, e2, a2)
    NODE_LOOP(e2, e3, a3)
#undef NODE_LOOP

    #pragma unroll
    for (int c = 0; c < 4; ++c) {
        a0[c] += __shfl_xor(a0[c], 16, 64); a0[c] += __shfl_xor(a0[c], 32, 64);
        a1[c] += __shfl_xor(a1[c], 16, 64); a1[c] += __shfl_xor(a1[c], 32, 64);
        a2[c] += __shfl_xor(a2[c], 16, 64); a2[c] += __shfl_xor(a2[c], 32, 64);
        a3[c] += __shfl_xor(a3[c], 16, 64); a3[c] += __shfl_xor(a3[c], 32, 64);
    }

    {
        const int node = nb + slot;
        const float di = dinv[node];
        const float di2 = di * di;
        f32x4 av = a0;
        if (slot == 1) av = a1;
        if (slot == 2) av = a2;
        if (slot == 3) av = a3;
        const size_t off = (size_t)node * 64 + cq;
        const f32x4 pv = *reinterpret_cast<const f32x4*>(prev + off);  // self loop
        const f32x4 hh = __builtin_nontemporal_load(
            reinterpret_cast<const f32x4*>(h0 + off));
        f32x4 r;
        #pragma unroll
        for (int c = 0; c < 4; ++c)
            r[c] = 0.9f * di2 * (av[c] + pv[c]) + 0.1f * hh[c];
        __builtin_nontemporal_store(r, reinterpret_cast<f32x4*>(next + off));
    }
}

// ---- log_softmax over 64 classes; input scaled planes, rescale by rd ----------
__launch_bounds__(256)
__global__ void logsm_k(const float* __restrict__ in, const float* __restrict__ rd,
                        float* __restrict__ out) {
    int r = (blockIdx.x * 256 + threadIdx.x) >> 6;
    int lane = threadIdx.x & 63;
    if (r >= N_NODES) return;
    float v = in[(size_t)r * 64 + lane] * rd[r];
    float m = v;
    #pragma unroll
    for (int d = 32; d; d >>= 1) m = fmaxf(m, __shfl_xor(m, d, 64));
    float e = __expf(v - m);
    float s = e;
    #pragma unroll
    for (int d = 32; d; d >>= 1) s += __shfl_xor(s, d, 64);
    out[(size_t)r * N_CLS + lane] = (v - m) - __logf(s);
}

extern "C" void kernel_launch(void* const* d_in, const int* in_sizes, int n_in,
                              void* d_out, int out_size, void* d_ws, size_t ws_size,
                              hipStream_t stream) {
    const float* X  = (const float*)d_in[0];
    const int*   EI = (const int*)d_in[1];
    const float* W1 = (const float*)d_in[2];
    const float* W2 = (const float*)d_in[3];
    const int* src = EI;
    const int* dst = EI + N_EDGES;

    char* ws = (char*)d_ws;
    // Lifetimes: Xb/W1b live [xb_k, gemm1]; hop-state reuses those bytes after.
    ushort* Xb     = (ushort*)(ws + 0);                 // 51,200,000 B
    ushort* W1b    = (ushort*)(ws + 51200000);          //    262,144 B
    ushort* H      = (ushort*)(ws + 51462144);          // 25,600,000 B
    // reuse of [0, 51.2MB) after gemm1:
    float*  h0t    = (float*)(ws + 0);                  // 12,804,096 B [NPAD][64]
    float*  pp0    = (float*)(ws + 12804096);           // 12,804,096 B
    float*  pp1    = (float*)(ws + 25608192);           // 12,804,096 B
    int*    csr    = (int*)  (ws + 38412288);           // <= 9,600,000 B
    int*    deg    = (int*)  (ws + 48012288);           //    200,000 B
    float*  dinv   = (float*)(ws + 48212288);           //    200,000 B
    float*  rd     = (float*)(ws + 48412288);           //    200,000 B
    int*    rptr   = (int*)  (ws + 48612288);           //    200,004 B
    int*    cursor = (int*)  (ws + 48812292);           //    200,000 B
    int*    part   = (int*)  (ws + 49012292);           //        784 B
    int*    coff   = (int*)  (ws + 49013076);           //        784 B

    // 1) convert X/W1 to bf16, then GEMM1 (uses only Xb/W1b/H)
    xb_k<<<12564, 256, 0, stream>>>(X, W1, Xb, W1b);
    gemm1_k<<<dim3(391, 2), 256, 0, stream>>>(Xb, W1b, H);

    // 2) Xb region now dead -> CSR build + hop-state setup in its place
    hipMemsetAsync(deg, 0, N_NODES * sizeof(int), stream);
    hipMemsetAsync(cursor, 0, N_NODES * sizeof(int), stream);
    deg_k<<<1563, 256, 0, stream>>>(dst, deg);
    dinv_k<<<196, 256, 0, stream>>>(deg, dinv, rd);
    scan_p1<<<196, 256, 0, stream>>>(deg, part);
    scan_p2<<<1, 256, 0, stream>>>(part, coff, rptr);
    scan_p3<<<196, 256, 0, stream>>>(deg, coff, rptr);
    scatter_k<<<12504, 256, 0, stream>>>(src, dst, rptr, cursor, csr);
    padfill_k<<<196, 256, 0, stream>>>(deg, rptr, csr);

    // 3) GEMM2 (reads H + dinv, writes h0t), then hops
    gemm2_k<<<391, 256, 0, stream>>>(H, W2, dinv, h0t);
    zdum_k<<<1, 256, 0, stream>>>(h0t, pp0, pp1);

    const float* p = h0t;
    float* bufs[2] = {pp0, pp1};
    for (int k = 0; k < K_HOPS; ++k) {
        float* nx = bufs[k & 1];
        hop_k<<<HOP_GRID, 256, 0, stream>>>(p, h0t, nx, csr, rptr, dinv);
        p = nx;
    }
    logsm_k<<<12500, 256, 0, stream>>>(p, rd, (float*)d_out);
}

// Round 13
// 492.406 us; speedup vs baseline: 1.4827x; 1.4827x over previous
//
#include <hip/hip_runtime.h>
#include <hip/hip_bf16.h>
#include <cstdint>
#include <cstddef>

#define N_NODES 50000
#define N_EDGES 1600000
#define N_FEAT  512
#define N_HID   256
#define N_CLS   64
#define K_HOPS  10
#define NPAD    50016                       // plane rows incl. dummy zero row
#define DUMMY   N_NODES                     // pad edges point here (zeroed)
#define P16(d) (((d) + 15) & ~15)
#define STAGE_CAP 256                       // csr entries staged in LDS per wave
#define HOP_GRID 3125                       // 16 nodes/block x 3125 = 50000
#define NPS 6250                            // nodes per XCD slice (scatter)

typedef __attribute__((ext_vector_type(4))) float f32x4;
typedef __attribute__((ext_vector_type(4))) int   i32x4;
typedef __attribute__((ext_vector_type(2))) unsigned int u32x2;
typedef __attribute__((ext_vector_type(4))) unsigned short u16x4;
typedef __attribute__((ext_vector_type(8))) short s16x8;

__device__ __forceinline__ ushort f2bf(float f) {
    uint32_t u = __float_as_uint(f);
    uint32_t r = (u + 0x7FFFu + ((u >> 16) & 1u)) >> 16;
    return (ushort)r;
}

// packed fp32x2 -> bf16x2, single VALU op. NON-volatile: pure, schedulable.
__device__ __forceinline__ uint32_t cvtpk(float a, float b) {
    uint32_t r;
    asm("v_cvt_pk_bf16_f32 %0, %1, %2" : "=v"(r) : "v"(a), "v"(b));
    return r;
}

__device__ __forceinline__ f32x4 bf4_to_f32(u16x4 v) {
    f32x4 r;
    r[0] = __uint_as_float((uint32_t)v[0] << 16);
    r[1] = __uint_as_float((uint32_t)v[1] << 16);
    r[2] = __uint_as_float((uint32_t)v[2] << 16);
    r[3] = __uint_as_float((uint32_t)v[3] << 16);
    return r;
}

// ------- prepass: X (and W1) fp32 -> bf16, pure streaming, full occupancy ------
__global__ void xb_k(const float* __restrict__ X, const float* __restrict__ W1,
                     ushort* __restrict__ Xb, ushort* __restrict__ W1b) {
    const size_t NX = (size_t)N_NODES * N_FEAT;   // 25,600,000
    const size_t NW = (size_t)N_HID * N_FEAT;     // 131,072
    size_t i = ((size_t)blockIdx.x * 256 + threadIdx.x) * 8;
    if (i < NX) {
        const f32x4 a = *reinterpret_cast<const f32x4*>(X + i);
        const f32x4 b = *reinterpret_cast<const f32x4*>(X + i + 4);
        uint4 o;
        o.x = cvtpk(a[0], a[1]); o.y = cvtpk(a[2], a[3]);
        o.z = cvtpk(b[0], b[1]); o.w = cvtpk(b[2], b[3]);
        *reinterpret_cast<uint4*>(Xb + i) = o;
    } else {
        size_t j = i - NX;
        if (j < NW) {
            const f32x4 a = *reinterpret_cast<const f32x4*>(W1 + j);
            const f32x4 b = *reinterpret_cast<const f32x4*>(W1 + j + 4);
            uint4 o;
            o.x = cvtpk(a[0], a[1]); o.y = cvtpk(a[2], a[3]);
            o.z = cvtpk(b[0], b[1]); o.w = cvtpk(b[2], b[3]);
            *reinterpret_cast<uint4*>(W1b + j) = o;
        }
    }
}

// ---- GEMM1: H = relu(Xb @ W1b^T), bf16 inputs, pure-copy staging --------------
__launch_bounds__(256)
__global__ void gemm1_k(const ushort* __restrict__ Xb, const ushort* __restrict__ W1b,
                        ushort* __restrict__ H) {
    __shared__ ushort sA[128 * 64];
    __shared__ ushort sB[128 * 64];
    const int m0 = blockIdx.x * 128;
    const int n0 = blockIdx.y * 128;
    const int t = threadIdx.x;
    const int wid = t >> 6, lane = t & 63;
    const int wr = wid >> 1, wc = wid & 1;
    const int lo = lane & 15, hi = lane >> 4;

    f32x4 acc[4][4] = {};

    for (int kt = 0; kt < N_FEAT; kt += 64) {
        #pragma unroll
        for (int p = 0; p < 4; ++p) {
            int idx = p * 256 + t;
            int row = idx >> 3, g = idx & 7;
            int grow = m0 + row; if (grow > N_NODES - 1) grow = N_NODES - 1;
            uint4 v = *reinterpret_cast<const uint4*>(Xb + (size_t)grow * N_FEAT + kt + g * 8);
            *reinterpret_cast<uint4*>(&sA[row * 64 + ((g ^ (row & 7)) << 3)]) = v;
        }
        #pragma unroll
        for (int p = 0; p < 4; ++p) {
            int idx = p * 256 + t;
            int row = idx >> 3, g = idx & 7;
            uint4 v = *reinterpret_cast<const uint4*>(W1b + (size_t)(n0 + row) * N_FEAT + kt + g * 8);
            *reinterpret_cast<uint4*>(&sB[row * 64 + ((g ^ (row & 7)) << 3)]) = v;
        }
        __syncthreads();
        #pragma unroll
        for (int kk = 0; kk < 2; ++kk) {
            const int g = kk * 4 + hi;
            s16x8 a[4], b[4];
            #pragma unroll
            for (int i = 0; i < 4; ++i) {
                int row = wr * 64 + i * 16 + lo;
                a[i] = *reinterpret_cast<const s16x8*>(&sA[row * 64 + ((g ^ (row & 7)) << 3)]);
            }
            #pragma unroll
            for (int j = 0; j < 4; ++j) {
                int row = wc * 64 + j * 16 + lo;
                b[j] = *reinterpret_cast<const s16x8*>(&sB[row * 64 + ((g ^ (row & 7)) << 3)]);
            }
            #pragma unroll
            for (int i = 0; i < 4; ++i)
                #pragma unroll
                for (int j = 0; j < 4; ++j)
                    acc[i][j] = __builtin_amdgcn_mfma_f32_16x16x32_bf16(a[i], b[j], acc[i][j], 0, 0, 0);
        }
        __syncthreads();
    }
    #pragma unroll
    for (int i = 0; i < 4; ++i) {
        int rbase = m0 + wr * 64 + i * 16 + hi * 4;
        #pragma unroll
        for (int j = 0; j < 4; ++j) {
            int col = n0 + wc * 64 + j * 16 + lo;
            #pragma unroll
            for (int r = 0; r < 4; ++r) {
                int row = rbase + r;
                if (row < N_NODES) {
                    float v = acc[i][j][r];
                    H[(size_t)row * N_HID + col] = f2bf(fmaxf(v, 0.0f));
                }
            }
        }
    }
}

// ---- GEMM2: h~0 = dinv * (H @ W2^T), row-major [NPAD][64] BF16 ----------------
__launch_bounds__(256)
__global__ void gemm2_k(const ushort* __restrict__ H, const float* __restrict__ W2,
                        const float* __restrict__ dinv, ushort* __restrict__ out) {
    __shared__ ushort sA[128 * 64];
    __shared__ ushort sB[64 * 64];
    const int m0 = blockIdx.x * 128;
    const int t = threadIdx.x;
    const int wid = t >> 6, lane = t & 63;
    const int lo = lane & 15, hi = lane >> 4;

    f32x4 acc[2][4] = {};

    for (int kt = 0; kt < N_HID; kt += 64) {
        #pragma unroll
        for (int p = 0; p < 4; ++p) {
            int idx = p * 256 + t;
            int row = idx >> 3, g = idx & 7;
            int grow = m0 + row; if (grow > N_NODES - 1) grow = N_NODES - 1;
            uint4 v = *reinterpret_cast<const uint4*>(H + (size_t)grow * N_HID + kt + g * 8);
            *reinterpret_cast<uint4*>(&sA[row * 64 + ((g ^ (row & 7)) << 3)]) = v;
        }
        #pragma unroll
        for (int p = 0; p < 4; ++p) {
            int idx = p * 256 + t;
            int row = idx >> 4, f4 = idx & 15;
            const float4 v = *reinterpret_cast<const float4*>(W2 + (size_t)row * N_HID + kt + f4 * 4);
            uint2 h; h.x = cvtpk(v.x, v.y); h.y = cvtpk(v.z, v.w);
            int g = f4 >> 1;
            int off = row * 64 + ((g ^ (row & 7)) << 3) + ((f4 & 1) << 2);
            *reinterpret_cast<uint2*>(&sB[off]) = h;
        }
        __syncthreads();
        #pragma unroll
        for (int kk = 0; kk < 2; ++kk) {
            const int g = kk * 4 + hi;
            s16x8 a[2], b[4];
            #pragma unroll
            for (int i = 0; i < 2; ++i) {
                int row = wid * 32 + i * 16 + lo;
                a[i] = *reinterpret_cast<const s16x8*>(&sA[row * 64 + ((g ^ (row & 7)) << 3)]);
            }
            #pragma unroll
            for (int j = 0; j < 4; ++j) {
                int row = j * 16 + lo;
                b[j] = *reinterpret_cast<const s16x8*>(&sB[row * 64 + ((g ^ (row & 7)) << 3)]);
            }
            #pragma unroll
            for (int i = 0; i < 2; ++i)
                #pragma unroll
                for (int j = 0; j < 4; ++j)
                    acc[i][j] = __builtin_amdgcn_mfma_f32_16x16x32_bf16(a[i], b[j], acc[i][j], 0, 0, 0);
        }
        __syncthreads();
    }
    // row-major bf16 store scaled by dinv: out[row][j*16+lo]
    #pragma unroll
    for (int i = 0; i < 2; ++i) {
        int rbase = m0 + wid * 32 + i * 16 + hi * 4;
        #pragma unroll
        for (int r = 0; r < 4; ++r) {
            int row = rbase + r;
            if (row < N_NODES) {
                const float dv = dinv[row];
                #pragma unroll
                for (int j = 0; j < 4; ++j)
                    out[(size_t)row * 64 + j * 16 + lo] = f2bf(acc[i][j][r] * dv);
            }
        }
    }
}

// ------- degree: unsliced, 4 edges/thread, NONTEMPORAL edge stream -------------
__global__ void deg_k(const int* __restrict__ dst, int* __restrict__ deg) {
    int e = (blockIdx.x * 256 + threadIdx.x) * 4;
    if (e + 3 < N_EDGES) {
        const i32x4 d = __builtin_nontemporal_load(
            reinterpret_cast<const i32x4*>(dst + e));
        atomicAdd(&deg[d[0]], 1);
        atomicAdd(&deg[d[1]], 1);
        atomicAdd(&deg[d[2]], 1);
        atomicAdd(&deg[d[3]], 1);
    } else {
        for (int k = 0; k < 4 && e + k < N_EDGES; ++k)
            atomicAdd(&deg[dst[e + k]], 1);
    }
}

__global__ void dinv_k(const int* __restrict__ deg, float* __restrict__ dinv,
                       float* __restrict__ rd) {
    int n = blockIdx.x * 256 + threadIdx.x;
    if (n < N_NODES) {
        float dp1 = (float)deg[n] + 1.0f;     // +1 self loop
        dinv[n] = rsqrtf(dp1);
        rd[n]   = sqrtf(dp1);
    }
}

// ------------- CSR build: scan over PADDED degrees + scatter + padfill ---------
__device__ __forceinline__ int wave_incl_scan(int v, int lane) {
    #pragma unroll
    for (int d = 1; d < 64; d <<= 1) {
        int u = __shfl_up(v, d, 64);
        if (lane >= d) v += u;
    }
    return v;
}

__global__ void scan_p1(const int* __restrict__ cnt, int* __restrict__ partial) {
    int i = blockIdx.x * 256 + threadIdx.x;
    int v = (i < N_NODES) ? P16(cnt[i]) : 0;
    #pragma unroll
    for (int d = 32; d; d >>= 1) v += __shfl_xor(v, d, 64);
    __shared__ int wt[4];
    int wid = threadIdx.x >> 6, lane = threadIdx.x & 63;
    if (lane == 0) wt[wid] = v;
    __syncthreads();
    if (threadIdx.x == 0) partial[blockIdx.x] = wt[0] + wt[1] + wt[2] + wt[3];
}

__global__ void scan_p2(const int* __restrict__ partial, int* __restrict__ chunkoff,
                        int* __restrict__ row_ptr) {
    int t = threadIdx.x;
    int v = (t < 196) ? partial[t] : 0;
    int lane = t & 63, wid = t >> 6;
    int incl = wave_incl_scan(v, lane);
    __shared__ int wt[4];
    if (lane == 63) wt[wid] = incl;
    __syncthreads();
    int woff = 0;
    for (int w = 0; w < wid; ++w) woff += wt[w];
    int excl = incl - v + woff;
    if (t < 196) chunkoff[t] = excl;
    if (t == 0) row_ptr[N_NODES] = wt[0] + wt[1] + wt[2] + wt[3];  // padded total
}

__global__ void scan_p3(const int* __restrict__ cnt, const int* __restrict__ chunkoff,
                        int* __restrict__ row_ptr) {
    int i = blockIdx.x * 256 + threadIdx.x;
    int v = (i < N_NODES) ? P16(cnt[i]) : 0;
    int lane = threadIdx.x & 63, wid = threadIdx.x >> 6;
    int incl = wave_incl_scan(v, lane);
    __shared__ int wt[4];
    if (lane == 63) wt[wid] = incl;
    __syncthreads();
    int woff = 0;
    for (int w = 0; w < wid; ++w) woff += wt[w];
    int excl = incl - v + woff;
    if (i < N_NODES) row_ptr[i] = chunkoff[blockIdx.x] + excl;
}

// ---- scatter: 8-way XCD-sliced; atomic traffic is the floor (r11) -------------
__global__ void scatter_k(const int* __restrict__ src, const int* __restrict__ dst,
                          const int* __restrict__ row_ptr,
                          int* __restrict__ cursor, int* __restrict__ csr) {
    const int slice = blockIdx.x & 7;
    const int lo = slice * NPS;
    int e = ((blockIdx.x >> 3) * 256 + threadIdx.x) * 4;
    if (e + 3 < N_EDGES) {
        const i32x4 d4 = __builtin_nontemporal_load(
            reinterpret_cast<const i32x4*>(dst + e));
        const i32x4 s4 = __builtin_nontemporal_load(
            reinterpret_cast<const i32x4*>(src + e));
        #pragma unroll
        for (int k = 0; k < 4; ++k) {
            const int d = d4[k];
            if ((unsigned)(d - lo) < (unsigned)NPS) {
                int pos = atomicAdd(&cursor[d], 1);
                csr[row_ptr[d] + pos] = s4[k];
            }
        }
    } else {
        for (int k = 0; k < 4 && e + k < N_EDGES; ++k) {
            int d = dst[e + k];
            if ((unsigned)(d - lo) < (unsigned)NPS) {
                int pos = atomicAdd(&cursor[d], 1);
                csr[row_ptr[d] + pos] = src[e + k];
            }
        }
    }
}

__global__ void padfill_k(const int* __restrict__ deg, const int* __restrict__ row_ptr,
                          int* __restrict__ csr) {
    int n = blockIdx.x * 256 + threadIdx.x;
    if (n >= N_NODES) return;
    int d = deg[n];
    int base = row_ptr[n] + d;
    int pad = P16(d) - d;
    for (int i = 0; i < pad; ++i) csr[base + i] = DUMMY;
}

// zero the dummy row (64 bf16) in the 3 state buffers
__global__ void zdum_k(ushort* __restrict__ b0, ushort* __restrict__ b1,
                       ushort* __restrict__ b2) {
    int t = threadIdx.x;
    if (t >= 192) return;
    ushort* b = (t < 64) ? b0 : (t < 128) ? b1 : b2;
    int w = t & 63;
    b[(size_t)DUMMY * 64 + w] = 0;
}

// ---------------- one APPNP hop: single-pass full-row, BF16 planes -------------
// p~'[d] = 0.9*dinv[d]^2*(sum_{s in N(d)} p~[s] + p~[d]) + 0.1*h~0[d]
// Planes row-major [NPAD][64] bf16 (128B rows, 6.4MB/plane -> better L2 fit,
// half the gather bytes of fp32; accumulation stays fp32 in-register).
// Wave = 4 edge-slots x 16 lanes x u16x4 (8B). 32-entry main loop = 8 gathers
// in flight/lane; 16-entry tail (P16 segments). 4 nodes/wave, csr LDS-staged.
__launch_bounds__(256)
__global__ void hop_k(const ushort* __restrict__ prev, const ushort* __restrict__ h0,
                      ushort* __restrict__ next, const int* __restrict__ csr,
                      const int* __restrict__ row_ptr, const float* __restrict__ dinv) {
    __shared__ int scsr[4][STAGE_CAP];
    const int bid = blockIdx.x;
    const int wid = threadIdx.x >> 6;
    const int lane = threadIdx.x & 63;
    const int nb = bid * 16 + wid * 4;             // first of this wave's 4 nodes
    const int slot = lane >> 4;                    // edge slot 0..3
    const int cq = (lane & 15) << 2;               // bf16 offset in 64-elem row

    const int b0 = __builtin_amdgcn_readfirstlane(row_ptr[nb]);
    const int e0 = __builtin_amdgcn_readfirstlane(row_ptr[nb + 1]);
    const int e1 = __builtin_amdgcn_readfirstlane(row_ptr[nb + 2]);
    const int e2 = __builtin_amdgcn_readfirstlane(row_ptr[nb + 3]);
    const int e3 = __builtin_amdgcn_readfirstlane(row_ptr[nb + 4]);
    const int tot = e3 - b0;

    int* sw = scsr[wid];
    #pragma unroll
    for (int k = 0; k < 4; ++k) {
        int off = k * 64 + lane;
        if (off < tot && off < STAGE_CAP)
            sw[off] = __builtin_nontemporal_load(csr + b0 + off);
    }

    f32x4 a0 = {0.f,0.f,0.f,0.f}, a1 = a0, a2 = a0, a3 = a0;

#define NODE_LOOP(Bg, Eg, ACC)                                                   \
    {                                                                            \
        int ib = (Bg);                                                           \
        for (; ib + 32 <= (Eg); ib += 32) {                                      \
            int s[8];                                                            \
            if (ib + 32 - b0 <= STAGE_CAP) {                                     \
                int base = ib - b0 + slot;                                       \
                _Pragma("unroll")                                                \
                for (int k = 0; k < 8; ++k) s[k] = sw[base + 4 * k];             \
            } else {                                                             \
                _Pragma("unroll")                                                \
                for (int k = 0; k < 8; ++k)                                      \
                    s[k] = __builtin_nontemporal_load(csr + ib + slot + 4 * k);  \
            }                                                                    \
            u16x4 p[8];                                                          \
            _Pragma("unroll")                                                    \
            for (int k = 0; k < 8; ++k)                                          \
                p[k] = *reinterpret_cast<const u16x4*>(prev + (size_t)s[k] * 64 + cq); \
            _Pragma("unroll")                                                    \
            for (int k = 0; k < 8; ++k) {                                        \
                const f32x4 f = bf4_to_f32(p[k]);                                \
                ACC[0] += f[0]; ACC[1] += f[1]; ACC[2] += f[2]; ACC[3] += f[3];  \
            }                                                                    \
        }                                                                        \
        if (ib < (Eg)) {                                                         \
            int s[4];                                                            \
            if (ib + 16 - b0 <= STAGE_CAP) {                                     \
                int base = ib - b0 + slot;                                       \
                _Pragma("unroll")                                                \
                for (int k = 0; k < 4; ++k) s[k] = sw[base + 4 * k];             \
            } else {                                                             \
                _Pragma("unroll")                                                \
                for (int k = 0; k < 4; ++k)                                      \
                    s[k] = __builtin_nontemporal_load(csr + ib + slot + 4 * k);  \
            }                                                                    \
            u16x4 p[4];                                                          \
            _Pragma("unroll")                                                    \
            for (int k = 0; k < 4; ++k)                                          \
                p[k] = *reinterpret_cast<const u16x4*>(prev + (size_t)s[k] * 64 + cq); \
            _Pragma("unroll")                                                    \
            for (int k = 0; k < 4; ++k) {                                        \
                const f32x4 f = bf4_to_f32(p[k]);                                \
                ACC[0] += f[0]; ACC[1] += f[1]; ACC[2] += f[2]; ACC[3] += f[3];  \
            }                                                                    \
        }                                                                        \
    }

    NODE_LOOP(b0, e0, a0)
    NODE_LOOP(e0, e1, a1)
    NODE_LOOP(e1, e2, a2)
    NODE_LOOP(e2, e3, a3)
#undef NODE_LOOP

    #pragma unroll
    for (int c = 0; c < 4; ++c) {
        a0[c] += __shfl_xor(a0[c], 16, 64); a0[c] += __shfl_xor(a0[c], 32, 64);
        a1[c] += __shfl_xor(a1[c], 16, 64); a1[c] += __shfl_xor(a1[c], 32, 64);
        a2[c] += __shfl_xor(a2[c], 16, 64); a2[c] += __shfl_xor(a2[c], 32, 64);
        a3[c] += __shfl_xor(a3[c], 16, 64); a3[c] += __shfl_xor(a3[c], 32, 64);
    }

    {
        const int node = nb + slot;
        const float di = dinv[node];
        const float di2 = di * di;
        f32x4 av = a0;
        if (slot == 1) av = a1;
        if (slot == 2) av = a2;
        if (slot == 3) av = a3;
        const size_t off = (size_t)node * 64 + cq;
        const f32x4 pv = bf4_to_f32(*reinterpret_cast<const u16x4*>(prev + off));
        const f32x4 hh = bf4_to_f32(__builtin_nontemporal_load(
            reinterpret_cast<const u16x4*>(h0 + off)));
        float r0 = 0.9f * di2 * (av[0] + pv[0]) + 0.1f * hh[0];
        float r1 = 0.9f * di2 * (av[1] + pv[1]) + 0.1f * hh[1];
        float r2 = 0.9f * di2 * (av[2] + pv[2]) + 0.1f * hh[2];
        float r3 = 0.9f * di2 * (av[3] + pv[3]) + 0.1f * hh[3];
        u32x2 o;
        o[0] = cvtpk(r0, r1);
        o[1] = cvtpk(r2, r3);
        __builtin_nontemporal_store(o, reinterpret_cast<u32x2*>(next + off));
    }
}

// ---- log_softmax over 64 classes; bf16 scaled planes, rescale by rd -----------
__launch_bounds__(256)
__global__ void logsm_k(const ushort* __restrict__ in, const float* __restrict__ rd,
                        float* __restrict__ out) {
    int r = (blockIdx.x * 256 + threadIdx.x) >> 6;
    int lane = threadIdx.x & 63;
    if (r >= N_NODES) return;
    float v = __uint_as_float((uint32_t)in[(size_t)r * 64 + lane] << 16) * rd[r];
    float m = v;
    #pragma unroll
    for (int d = 32; d; d >>= 1) m = fmaxf(m, __shfl_xor(m, d, 64));
    float e = __expf(v - m);
    float s = e;
    #pragma unroll
    for (int d = 32; d; d >>= 1) s += __shfl_xor(s, d, 64);
    out[(size_t)r * N_CLS + lane] = (v - m) - __logf(s);
}

extern "C" void kernel_launch(void* const* d_in, const int* in_sizes, int n_in,
                              void* d_out, int out_size, void* d_ws, size_t ws_size,
                              hipStream_t stream) {
    const float* X  = (const float*)d_in[0];
    const int*   EI = (const int*)d_in[1];
    const float* W1 = (const float*)d_in[2];
    const float* W2 = (const float*)d_in[3];
    const int* src = EI;
    const int* dst = EI + N_EDGES;

    char* ws = (char*)d_ws;
    // Lifetimes: Xb/W1b live [xb_k, gemm1]; hop-state reuses those bytes after.
    ushort* Xb     = (ushort*)(ws + 0);                 // 51,200,000 B
    ushort* W1b    = (ushort*)(ws + 51200000);          //    262,144 B
    ushort* H      = (ushort*)(ws + 51462144);          // 25,600,000 B
    // reuse of [0, 51.2MB) after gemm1 (bf16 planes: 6,402,048 B each):
    ushort* h0t    = (ushort*)(ws + 0);                 // [NPAD][64] bf16
    ushort* pp0    = (ushort*)(ws + 6402048);
    ushort* pp1    = (ushort*)(ws + 12804096);          // ends 19,206,144
    int*    csr    = (int*)  (ws + 19206144);           // <= 9,600,000 B
    int*    deg    = (int*)  (ws + 28806144);           //    200,000 B
    float*  dinv   = (float*)(ws + 29006144);           //    200,000 B
    float*  rd     = (float*)(ws + 29206144);           //    200,000 B
    int*    rptr   = (int*)  (ws + 29406144);           //    200,004 B
    int*    cursor = (int*)  (ws + 29606148);           //    200,000 B
    int*    part   = (int*)  (ws + 29806148);           //        784 B
    int*    coff   = (int*)  (ws + 29806932);           //        784 B

    // 1) convert X/W1 to bf16, then GEMM1 (uses only Xb/W1b/H)
    xb_k<<<12564, 256, 0, stream>>>(X, W1, Xb, W1b);
    gemm1_k<<<dim3(391, 2), 256, 0, stream>>>(Xb, W1b, H);

    // 2) Xb region now dead -> CSR build + hop-state setup in its place
    hipMemsetAsync(deg, 0, N_NODES * sizeof(int), stream);
    hipMemsetAsync(cursor, 0, N_NODES * sizeof(int), stream);
    deg_k<<<1563, 256, 0, stream>>>(dst, deg);
    dinv_k<<<196, 256, 0, stream>>>(deg, dinv, rd);
    scan_p1<<<196, 256, 0, stream>>>(deg, part);
    scan_p2<<<1, 256, 0, stream>>>(part, coff, rptr);
    scan_p3<<<196, 256, 0, stream>>>(deg, coff, rptr);
    scatter_k<<<12504, 256, 0, stream>>>(src, dst, rptr, cursor, csr);
    padfill_k<<<196, 256, 0, stream>>>(deg, rptr, csr);

    // 3) GEMM2 (reads H + dinv, writes bf16 h0t), then hops
    gemm2_k<<<391, 256, 0, stream>>>(H, W2, dinv, h0t);
    zdum_k<<<1, 256, 0, stream>>>(h0t, pp0, pp1);

    const ushort* p = h0t;
    ushort* bufs[2] = {pp0, pp1};
    for (int k = 0; k < K_HOPS; ++k) {
        ushort* nx = bufs[k & 1];
        hop_k<<<HOP_GRID, 256, 0, stream>>>(p, h0t, nx, csr, rptr, dinv);
        p = nx;
    }
    logsm_k<<<12500, 256, 0, stream>>>(p, rd, (float*)d_out);
}

// Round 14
// 452.316 us; speedup vs baseline: 1.6141x; 1.0886x over previous
//
#include <hip/hip_runtime.h>
#include <hip/hip_bf16.h>
#include <cstdint>
#include <cstddef>

#define N_NODES 50000
#define N_EDGES 1600000
#define N_FEAT  512
#define N_HID   256
#define N_CLS   64
#define K_HOPS  10
#define NPAD    50016                       // plane rows incl. dummy zero row
#define DUMMY   N_NODES                     // pad edges point here (zeroed)
#define P16(d) (((d) + 15) & ~15)
#define STAGE_CAP 256                       // csr entries staged in LDS per wave
#define HOP_GRID 3125                       // 16 nodes/block x 3125 = 50000

typedef __attribute__((ext_vector_type(4))) float f32x4;
typedef __attribute__((ext_vector_type(4))) int   i32x4;
typedef __attribute__((ext_vector_type(2))) unsigned int u32x2;
typedef __attribute__((ext_vector_type(4))) unsigned short u16x4;
typedef __attribute__((ext_vector_type(8))) short s16x8;

__device__ __forceinline__ ushort f2bf(float f) {
    uint32_t u = __float_as_uint(f);
    uint32_t r = (u + 0x7FFFu + ((u >> 16) & 1u)) >> 16;
    return (ushort)r;
}

// packed fp32x2 -> bf16x2, single VALU op. NON-volatile: pure, schedulable.
__device__ __forceinline__ uint32_t cvtpk(float a, float b) {
    uint32_t r;
    asm("v_cvt_pk_bf16_f32 %0, %1, %2" : "=v"(r) : "v"(a), "v"(b));
    return r;
}

__device__ __forceinline__ f32x4 bf4_to_f32(u16x4 v) {
    f32x4 r;
    r[0] = __uint_as_float((uint32_t)v[0] << 16);
    r[1] = __uint_as_float((uint32_t)v[1] << 16);
    r[2] = __uint_as_float((uint32_t)v[2] << 16);
    r[3] = __uint_as_float((uint32_t)v[3] << 16);
    return r;
}

// ------- prepass: X (and W1) fp32 -> bf16, pure streaming, full occupancy ------
__global__ void xb_k(const float* __restrict__ X, const float* __restrict__ W1,
                     ushort* __restrict__ Xb, ushort* __restrict__ W1b) {
    const size_t NX = (size_t)N_NODES * N_FEAT;   // 25,600,000
    const size_t NW = (size_t)N_HID * N_FEAT;     // 131,072
    size_t i = ((size_t)blockIdx.x * 256 + threadIdx.x) * 8;
    if (i < NX) {
        const f32x4 a = *reinterpret_cast<const f32x4*>(X + i);
        const f32x4 b = *reinterpret_cast<const f32x4*>(X + i + 4);
        uint4 o;
        o.x = cvtpk(a[0], a[1]); o.y = cvtpk(a[2], a[3]);
        o.z = cvtpk(b[0], b[1]); o.w = cvtpk(b[2], b[3]);
        *reinterpret_cast<uint4*>(Xb + i) = o;
    } else {
        size_t j = i - NX;
        if (j < NW) {
            const f32x4 a = *reinterpret_cast<const f32x4*>(W1 + j);
            const f32x4 b = *reinterpret_cast<const f32x4*>(W1 + j + 4);
            uint4 o;
            o.x = cvtpk(a[0], a[1]); o.y = cvtpk(a[2], a[3]);
            o.z = cvtpk(b[0], b[1]); o.w = cvtpk(b[2], b[3]);
            *reinterpret_cast<uint4*>(W1b + j) = o;
        }
    }
}

// ---- GEMM1: H = relu(Xb @ W1b^T), bf16 inputs, pure-copy staging --------------
__launch_bounds__(256)
__global__ void gemm1_k(const ushort* __restrict__ Xb, const ushort* __restrict__ W1b,
                        ushort* __restrict__ H) {
    __shared__ ushort sA[128 * 64];
    __shared__ ushort sB[128 * 64];
    const int m0 = blockIdx.x * 128;
    const int n0 = blockIdx.y * 128;
    const int t = threadIdx.x;
    const int wid = t >> 6, lane = t & 63;
    const int wr = wid >> 1, wc = wid & 1;
    const int lo = lane & 15, hi = lane >> 4;

    f32x4 acc[4][4] = {};

    for (int kt = 0; kt < N_FEAT; kt += 64) {
        #pragma unroll
        for (int p = 0; p < 4; ++p) {
            int idx = p * 256 + t;
            int row = idx >> 3, g = idx & 7;
            int grow = m0 + row; if (grow > N_NODES - 1) grow = N_NODES - 1;
            uint4 v = *reinterpret_cast<const uint4*>(Xb + (size_t)grow * N_FEAT + kt + g * 8);
            *reinterpret_cast<uint4*>(&sA[row * 64 + ((g ^ (row & 7)) << 3)]) = v;
        }
        #pragma unroll
        for (int p = 0; p < 4; ++p) {
            int idx = p * 256 + t;
            int row = idx >> 3, g = idx & 7;
            uint4 v = *reinterpret_cast<const uint4*>(W1b + (size_t)(n0 + row) * N_FEAT + kt + g * 8);
            *reinterpret_cast<uint4*>(&sB[row * 64 + ((g ^ (row & 7)) << 3)]) = v;
        }
        __syncthreads();
        #pragma unroll
        for (int kk = 0; kk < 2; ++kk) {
            const int g = kk * 4 + hi;
            s16x8 a[4], b[4];
            #pragma unroll
            for (int i = 0; i < 4; ++i) {
                int row = wr * 64 + i * 16 + lo;
                a[i] = *reinterpret_cast<const s16x8*>(&sA[row * 64 + ((g ^ (row & 7)) << 3)]);
            }
            #pragma unroll
            for (int j = 0; j < 4; ++j) {
                int row = wc * 64 + j * 16 + lo;
                b[j] = *reinterpret_cast<const s16x8*>(&sB[row * 64 + ((g ^ (row & 7)) << 3)]);
            }
            #pragma unroll
            for (int i = 0; i < 4; ++i)
                #pragma unroll
                for (int j = 0; j < 4; ++j)
                    acc[i][j] = __builtin_amdgcn_mfma_f32_16x16x32_bf16(a[i], b[j], acc[i][j], 0, 0, 0);
        }
        __syncthreads();
    }
    #pragma unroll
    for (int i = 0; i < 4; ++i) {
        int rbase = m0 + wr * 64 + i * 16 + hi * 4;
        #pragma unroll
        for (int j = 0; j < 4; ++j) {
            int col = n0 + wc * 64 + j * 16 + lo;
            #pragma unroll
            for (int r = 0; r < 4; ++r) {
                int row = rbase + r;
                if (row < N_NODES) {
                    float v = acc[i][j][r];
                    H[(size_t)row * N_HID + col] = f2bf(fmaxf(v, 0.0f));
                }
            }
        }
    }
}

// ---- GEMM2: h~0 = dinv * (H @ W2^T), row-major [NPAD][64] BF16 ----------------
__launch_bounds__(256)
__global__ void gemm2_k(const ushort* __restrict__ H, const float* __restrict__ W2,
                        const float* __restrict__ dinv, ushort* __restrict__ out) {
    __shared__ ushort sA[128 * 64];
    __shared__ ushort sB[64 * 64];
    const int m0 = blockIdx.x * 128;
    const int t = threadIdx.x;
    const int wid = t >> 6, lane = t & 63;
    const int lo = lane & 15, hi = lane >> 4;

    f32x4 acc[2][4] = {};

    for (int kt = 0; kt < N_HID; kt += 64) {
        #pragma unroll
        for (int p = 0; p < 4; ++p) {
            int idx = p * 256 + t;
            int row = idx >> 3, g = idx & 7;
            int grow = m0 + row; if (grow > N_NODES - 1) grow = N_NODES - 1;
            uint4 v = *reinterpret_cast<const uint4*>(H + (size_t)grow * N_HID + kt + g * 8);
            *reinterpret_cast<uint4*>(&sA[row * 64 + ((g ^ (row & 7)) << 3)]) = v;
        }
        #pragma unroll
        for (int p = 0; p < 4; ++p) {
            int idx = p * 256 + t;
            int row = idx >> 4, f4 = idx & 15;
            const float4 v = *reinterpret_cast<const float4*>(W2 + (size_t)row * N_HID + kt + f4 * 4);
            uint2 h; h.x = cvtpk(v.x, v.y); h.y = cvtpk(v.z, v.w);
            int g = f4 >> 1;
            int off = row * 64 + ((g ^ (row & 7)) << 3) + ((f4 & 1) << 2);
            *reinterpret_cast<uint2*>(&sB[off]) = h;
        }
        __syncthreads();
        #pragma unroll
        for (int kk = 0; kk < 2; ++kk) {
            const int g = kk * 4 + hi;
            s16x8 a[2], b[4];
            #pragma unroll
            for (int i = 0; i < 2; ++i) {
                int row = wid * 32 + i * 16 + lo;
                a[i] = *reinterpret_cast<const s16x8*>(&sA[row * 64 + ((g ^ (row & 7)) << 3)]);
            }
            #pragma unroll
            for (int j = 0; j < 4; ++j) {
                int row = j * 16 + lo;
                b[j] = *reinterpret_cast<const s16x8*>(&sB[row * 64 + ((g ^ (row & 7)) << 3)]);
            }
            #pragma unroll
            for (int i = 0; i < 2; ++i)
                #pragma unroll
                for (int j = 0; j < 4; ++j)
                    acc[i][j] = __builtin_amdgcn_mfma_f32_16x16x32_bf16(a[i], b[j], acc[i][j], 0, 0, 0);
        }
        __syncthreads();
    }
    // row-major bf16 store scaled by dinv: out[row][j*16+lo]
    #pragma unroll
    for (int i = 0; i < 2; ++i) {
        int rbase = m0 + wid * 32 + i * 16 + hi * 4;
        #pragma unroll
        for (int r = 0; r < 4; ++r) {
            int row = rbase + r;
            if (row < N_NODES) {
                const float dv = dinv[row];
                #pragma unroll
                for (int j = 0; j < 4; ++j)
                    out[(size_t)row * 64 + j * 16 + lo] = f2bf(acc[i][j][r] * dv);
            }
        }
    }
}

// ------- degree + position: atomicAdd RETURN VALUE is the scatter position -----
// One atomic pass serves both deg (for scan) and pos (for atomic-free scatter).
__global__ void deg_k(const int* __restrict__ dst, int* __restrict__ deg,
                      int* __restrict__ pos) {
    int e = (blockIdx.x * 256 + threadIdx.x) * 4;
    if (e + 3 < N_EDGES) {
        const i32x4 d = __builtin_nontemporal_load(
            reinterpret_cast<const i32x4*>(dst + e));
        i32x4 p;
        p[0] = atomicAdd(&deg[d[0]], 1);
        p[1] = atomicAdd(&deg[d[1]], 1);
        p[2] = atomicAdd(&deg[d[2]], 1);
        p[3] = atomicAdd(&deg[d[3]], 1);
        __builtin_nontemporal_store(p, reinterpret_cast<i32x4*>(pos + e));
    } else {
        for (int k = 0; k < 4 && e + k < N_EDGES; ++k)
            pos[e + k] = atomicAdd(&deg[dst[e + k]], 1);
    }
}

__global__ void dinv_k(const int* __restrict__ deg, float* __restrict__ dinv,
                       float* __restrict__ rd) {
    int n = blockIdx.x * 256 + threadIdx.x;
    if (n < N_NODES) {
        float dp1 = (float)deg[n] + 1.0f;     // +1 self loop
        dinv[n] = rsqrtf(dp1);
        rd[n]   = sqrtf(dp1);
    }
}

// ------------- CSR build: scan over PADDED degrees + scatter + padfill ---------
__device__ __forceinline__ int wave_incl_scan(int v, int lane) {
    #pragma unroll
    for (int d = 1; d < 64; d <<= 1) {
        int u = __shfl_up(v, d, 64);
        if (lane >= d) v += u;
    }
    return v;
}

__global__ void scan_p1(const int* __restrict__ cnt, int* __restrict__ partial) {
    int i = blockIdx.x * 256 + threadIdx.x;
    int v = (i < N_NODES) ? P16(cnt[i]) : 0;
    #pragma unroll
    for (int d = 32; d; d >>= 1) v += __shfl_xor(v, d, 64);
    __shared__ int wt[4];
    int wid = threadIdx.x >> 6, lane = threadIdx.x & 63;
    if (lane == 0) wt[wid] = v;
    __syncthreads();
    if (threadIdx.x == 0) partial[blockIdx.x] = wt[0] + wt[1] + wt[2] + wt[3];
}

__global__ void scan_p2(const int* __restrict__ partial, int* __restrict__ chunkoff,
                        int* __restrict__ row_ptr) {
    int t = threadIdx.x;
    int v = (t < 196) ? partial[t] : 0;
    int lane = t & 63, wid = t >> 6;
    int incl = wave_incl_scan(v, lane);
    __shared__ int wt[4];
    if (lane == 63) wt[wid] = incl;
    __syncthreads();
    int woff = 0;
    for (int w = 0; w < wid; ++w) woff += wt[w];
    int excl = incl - v + woff;
    if (t < 196) chunkoff[t] = excl;
    if (t == 0) row_ptr[N_NODES] = wt[0] + wt[1] + wt[2] + wt[3];  // padded total
}

__global__ void scan_p3(const int* __restrict__ cnt, const int* __restrict__ chunkoff,
                        int* __restrict__ row_ptr) {
    int i = blockIdx.x * 256 + threadIdx.x;
    int v = (i < N_NODES) ? P16(cnt[i]) : 0;
    int lane = threadIdx.x & 63, wid = threadIdx.x >> 6;
    int incl = wave_incl_scan(v, lane);
    __shared__ int wt[4];
    if (lane == 63) wt[wid] = incl;
    __syncthreads();
    int woff = 0;
    for (int w = 0; w < wid; ++w) woff += wt[w];
    int excl = incl - v + woff;
    if (i < N_NODES) row_ptr[i] = chunkoff[blockIdx.x] + excl;
}

// ---- scatter: ATOMIC-FREE. pos[] from deg_k; row_ptr gather is L2-resident ----
__global__ void scatter_k(const int* __restrict__ src, const int* __restrict__ dst,
                          const int* __restrict__ pos, const int* __restrict__ row_ptr,
                          int* __restrict__ csr) {
    int e = (blockIdx.x * 256 + threadIdx.x) * 4;
    if (e + 3 < N_EDGES) {
        const i32x4 d4 = __builtin_nontemporal_load(
            reinterpret_cast<const i32x4*>(dst + e));
        const i32x4 s4 = __builtin_nontemporal_load(
            reinterpret_cast<const i32x4*>(src + e));
        const i32x4 p4 = __builtin_nontemporal_load(
            reinterpret_cast<const i32x4*>(pos + e));
        #pragma unroll
        for (int k = 0; k < 4; ++k)
            csr[row_ptr[d4[k]] + p4[k]] = s4[k];
    } else {
        for (int k = 0; k < 4 && e + k < N_EDGES; ++k)
            csr[row_ptr[dst[e + k]] + pos[e + k]] = src[e + k];
    }
}

__global__ void padfill_k(const int* __restrict__ deg, const int* __restrict__ row_ptr,
                          int* __restrict__ csr) {
    int n = blockIdx.x * 256 + threadIdx.x;
    if (n >= N_NODES) return;
    int d = deg[n];
    int base = row_ptr[n] + d;
    int pad = P16(d) - d;
    for (int i = 0; i < pad; ++i) csr[base + i] = DUMMY;
}

// zero the dummy row (64 bf16) in the 3 state buffers
__global__ void zdum_k(ushort* __restrict__ b0, ushort* __restrict__ b1,
                       ushort* __restrict__ b2) {
    int t = threadIdx.x;
    if (t >= 192) return;
    ushort* b = (t < 64) ? b0 : (t < 128) ? b1 : b2;
    int w = t & 63;
    b[(size_t)DUMMY * 64 + w] = 0;
}

// ---------------- one APPNP hop: single-pass full-row, BF16 planes -------------
// p~'[d] = 0.9*dinv[d]^2*(sum_{s in N(d)} p~[s] + p~[d]) + 0.1*h~0[d]
// Planes row-major [NPAD][64] bf16 (128B rows, 6.4MB/plane; fp32 accum).
// Wave = 4 edge-slots x 16 lanes x u16x4 (8B). 32-entry main loop = 8 gathers
// in flight/lane; 16-entry tail (P16 segments). 4 nodes/wave, csr LDS-staged.
__launch_bounds__(256)
__global__ void hop_k(const ushort* __restrict__ prev, const ushort* __restrict__ h0,
                      ushort* __restrict__ next, const int* __restrict__ csr,
                      const int* __restrict__ row_ptr, const float* __restrict__ dinv) {
    __shared__ int scsr[4][STAGE_CAP];
    const int bid = blockIdx.x;
    const int wid = threadIdx.x >> 6;
    const int lane = threadIdx.x & 63;
    const int nb = bid * 16 + wid * 4;             // first of this wave's 4 nodes
    const int slot = lane >> 4;                    // edge slot 0..3
    const int cq = (lane & 15) << 2;               // bf16 offset in 64-elem row

    const int b0 = __builtin_amdgcn_readfirstlane(row_ptr[nb]);
    const int e0 = __builtin_amdgcn_readfirstlane(row_ptr[nb + 1]);
    const int e1 = __builtin_amdgcn_readfirstlane(row_ptr[nb + 2]);
    const int e2 = __builtin_amdgcn_readfirstlane(row_ptr[nb + 3]);
    const int e3 = __builtin_amdgcn_readfirstlane(row_ptr[nb + 4]);
    const int tot = e3 - b0;

    int* sw = scsr[wid];
    #pragma unroll
    for (int k = 0; k < 4; ++k) {
        int off = k * 64 + lane;
        if (off < tot && off < STAGE_CAP)
            sw[off] = __builtin_nontemporal_load(csr + b0 + off);
    }

    f32x4 a0 = {0.f,0.f,0.f,0.f}, a1 = a0, a2 = a0, a3 = a0;

#define NODE_LOOP(Bg, Eg, ACC)                                                   \
    {                                                                            \
        int ib = (Bg);                                                           \
        for (; ib + 32 <= (Eg); ib += 32) {                                      \
            int s[8];                                                            \
            if (ib + 32 - b0 <= STAGE_CAP) {                                     \
                int base = ib - b0 + slot;                                       \
                _Pragma("unroll")                                                \
                for (int k = 0; k < 8; ++k) s[k] = sw[base + 4 * k];             \
            } else {                                                             \
                _Pragma("unroll")                                                \
                for (int k = 0; k < 8; ++k)                                      \
                    s[k] = __builtin_nontemporal_load(csr + ib + slot + 4 * k);  \
            }                                                                    \
            u16x4 p[8];                                                          \
            _Pragma("unroll")                                                    \
            for (int k = 0; k < 8; ++k)                                          \
                p[k] = *reinterpret_cast<const u16x4*>(prev + (size_t)s[k] * 64 + cq); \
            _Pragma("unroll")                                                    \
            for (int k = 0; k < 8; ++k) {                                        \
                const f32x4 f = bf4_to_f32(p[k]);                                \
                ACC[0] += f[0]; ACC[1] += f[1]; ACC[2] += f[2]; ACC[3] += f[3];  \
            }                                                                    \
        }                                                                        \
        if (ib < (Eg)) {                                                         \
            int s[4];                                                            \
            if (ib + 16 - b0 <= STAGE_CAP) {                                     \
                int base = ib - b0 + slot;                                       \
                _Pragma("unroll")                                                \
                for (int k = 0; k < 4; ++k) s[k] = sw[base + 4 * k];             \
            } else {                                                             \
                _Pragma("unroll")                                                \
                for (int k = 0; k < 4; ++k)                                      \
                    s[k] = __builtin_nontemporal_load(csr + ib + slot + 4 * k);  \
            }                                                                    \
            u16x4 p[4];                                                          \
            _Pragma("unroll")                                                    \
            for (int k = 0; k < 4; ++k)                                          \
                p[k] = *reinterpret_cast<const u16x4*>(prev + (size_t)s[k] * 64 + cq); \
            _Pragma("unroll")                                                    \
            for (int k = 0; k < 4; ++k) {                                        \
                const f32x4 f = bf4_to_f32(p[k]);                                \
                ACC[0] += f[0]; ACC[1] += f[1]; ACC[2] += f[2]; ACC[3] += f[3];  \
            }                                                                    \
        }                                                                        \
    }

    NODE_LOOP(b0, e0, a0)
    NODE_LOOP(e0, e1, a1)
    NODE_LOOP(e1, e2, a2)
    NODE_LOOP(e2, e3, a3)
#undef NODE_LOOP

    #pragma unroll
    for (int c = 0; c < 4; ++c) {
        a0[c] += __shfl_xor(a0[c], 16, 64); a0[c] += __shfl_xor(a0[c], 32, 64);
        a1[c] += __shfl_xor(a1[c], 16, 64); a1[c] += __shfl_xor(a1[c], 32, 64);
        a2[c] += __shfl_xor(a2[c], 16, 64); a2[c] += __shfl_xor(a2[c], 32, 64);
        a3[c] += __shfl_xor(a3[c], 16, 64); a3[c] += __shfl_xor(a3[c], 32, 64);
    }

    {
        const int node = nb + slot;
        const float di = dinv[node];
        const float di2 = di * di;
        f32x4 av = a0;
        if (slot == 1) av = a1;
        if (slot == 2) av = a2;
        if (slot == 3) av = a3;
        const size_t off = (size_t)node * 64 + cq;
        const f32x4 pv = bf4_to_f32(*reinterpret_cast<const u16x4*>(prev + off));
        const f32x4 hh = bf4_to_f32(__builtin_nontemporal_load(
            reinterpret_cast<const u16x4*>(h0 + off)));
        float r0 = 0.9f * di2 * (av[0] + pv[0]) + 0.1f * hh[0];
        float r1 = 0.9f * di2 * (av[1] + pv[1]) + 0.1f * hh[1];
        float r2 = 0.9f * di2 * (av[2] + pv[2]) + 0.1f * hh[2];
        float r3 = 0.9f * di2 * (av[3] + pv[3]) + 0.1f * hh[3];
        u32x2 o;
        o[0] = cvtpk(r0, r1);
        o[1] = cvtpk(r2, r3);
        __builtin_nontemporal_store(o, reinterpret_cast<u32x2*>(next + off));
    }
}

// ---- log_softmax over 64 classes; bf16 scaled planes, rescale by rd -----------
__launch_bounds__(256)
__global__ void logsm_k(const ushort* __restrict__ in, const float* __restrict__ rd,
                        float* __restrict__ out) {
    int r = (blockIdx.x * 256 + threadIdx.x) >> 6;
    int lane = threadIdx.x & 63;
    if (r >= N_NODES) return;
    float v = __uint_as_float((uint32_t)in[(size_t)r * 64 + lane] << 16) * rd[r];
    float m = v;
    #pragma unroll
    for (int d = 32; d; d >>= 1) m = fmaxf(m, __shfl_xor(m, d, 64));
    float e = __expf(v - m);
    float s = e;
    #pragma unroll
    for (int d = 32; d; d >>= 1) s += __shfl_xor(s, d, 64);
    out[(size_t)r * N_CLS + lane] = (v - m) - __logf(s);
}

extern "C" void kernel_launch(void* const* d_in, const int* in_sizes, int n_in,
                              void* d_out, int out_size, void* d_ws, size_t ws_size,
                              hipStream_t stream) {
    const float* X  = (const float*)d_in[0];
    const int*   EI = (const int*)d_in[1];
    const float* W1 = (const float*)d_in[2];
    const float* W2 = (const float*)d_in[3];
    const int* src = EI;
    const int* dst = EI + N_EDGES;

    char* ws = (char*)d_ws;
    // Lifetimes: Xb/W1b live [xb_k, gemm1]; hop-state reuses those bytes after.
    ushort* Xb     = (ushort*)(ws + 0);                 // 51,200,000 B
    ushort* W1b    = (ushort*)(ws + 51200000);          //    262,144 B
    ushort* H      = (ushort*)(ws + 51462144);          // 25,600,000 B
    // reuse of [0, 51.2MB) after gemm1 (bf16 planes: 6,402,048 B each):
    ushort* h0t    = (ushort*)(ws + 0);                 // [NPAD][64] bf16
    ushort* pp0    = (ushort*)(ws + 6402048);
    ushort* pp1    = (ushort*)(ws + 12804096);          // ends 19,206,144
    int*    csr    = (int*)  (ws + 19206144);           // <= 9,600,000 B
    int*    deg    = (int*)  (ws + 28806144);           //    200,000 B
    float*  dinv   = (float*)(ws + 29006144);           //    200,000 B
    float*  rd     = (float*)(ws + 29206144);           //    200,000 B
    int*    rptr   = (int*)  (ws + 29406144);           //    200,004 B
    int*    part   = (int*)  (ws + 29606148);           //        784 B
    int*    coff   = (int*)  (ws + 29606932);           //        784 B
    int*    pos    = (int*)  (ws + 29607744);           //  6,400,000 B (ends 36MB)

    // 1) convert X/W1 to bf16, then GEMM1 (uses only Xb/W1b/H)
    xb_k<<<12564, 256, 0, stream>>>(X, W1, Xb, W1b);
    gemm1_k<<<dim3(391, 2), 256, 0, stream>>>(Xb, W1b, H);

    // 2) Xb region now dead -> CSR build + hop-state setup in its place
    hipMemsetAsync(deg, 0, N_NODES * sizeof(int), stream);
    deg_k<<<1563, 256, 0, stream>>>(dst, deg, pos);
    dinv_k<<<196, 256, 0, stream>>>(deg, dinv, rd);
    scan_p1<<<196, 256, 0, stream>>>(deg, part);
    scan_p2<<<1, 256, 0, stream>>>(part, coff, rptr);
    scan_p3<<<196, 256, 0, stream>>>(deg, coff, rptr);
    scatter_k<<<1563, 256, 0, stream>>>(src, dst, pos, rptr, csr);
    padfill_k<<<196, 256, 0, stream>>>(deg, rptr, csr);

    // 3) GEMM2 (reads H + dinv, writes bf16 h0t), then hops
    gemm2_k<<<391, 256, 0, stream>>>(H, W2, dinv, h0t);
    zdum_k<<<1, 256, 0, stream>>>(h0t, pp0, pp1);

    const ushort* p = h0t;
    ushort* bufs[2] = {pp0, pp1};
    for (int k = 0; k < K_HOPS; ++k) {
        ushort* nx = bufs[k & 1];
        hop_k<<<HOP_GRID, 256, 0, stream>>>(p, h0t, nx, csr, rptr, dinv);
        p = nx;
    }
    logsm_k<<<12500, 256, 0, stream>>>(p, rd, (float*)d_out);
}

// Round 16
// 406.601 us; speedup vs baseline: 1.7956x; 1.1124x over previous
//
#include <hip/hip_runtime.h>
#include <hip/hip_bf16.h>
#include <cstdint>
#include <cstddef>

#define N_NODES 50000
#define N_EDGES 1600000
#define N_FEAT  512
#define N_HID   256
#define N_CLS   64
#define K_HOPS  10
#define NPAD    50016                       // plane rows incl. dummy zero row
#define DUMMY   N_NODES                     // pad edges point here (zeroed)
#define P16(d) (((d) + 15) & ~15)
#define STAGE_CAP 256                       // csr entries staged in LDS per wave
#define HOP_GRID 3125                       // 16 nodes/block x 3125 = 50000
#define G1_BLOCKS 782                       // 391 x 2 gemm1 tiles
#define DEG_BLOCKS 1563                     // 4 edges/thread
#define G2_BLOCKS 391
#define SCAT_BLOCKS 1563

typedef __attribute__((ext_vector_type(4))) float f32x4;
typedef __attribute__((ext_vector_type(4))) int   i32x4;
typedef __attribute__((ext_vector_type(2))) unsigned int u32x2;
typedef __attribute__((ext_vector_type(4))) unsigned short u16x4;
typedef __attribute__((ext_vector_type(8))) short s16x8;

__device__ __forceinline__ ushort f2bf(float f) {
    uint32_t u = __float_as_uint(f);
    uint32_t r = (u + 0x7FFFu + ((u >> 16) & 1u)) >> 16;
    return (ushort)r;
}

// packed fp32x2 -> bf16x2, single VALU op. NON-volatile: pure, schedulable.
// (r7 lesson: volatile pins program order and serializes staging loads.)
__device__ __forceinline__ uint32_t cvtpk(float a, float b) {
    uint32_t r;
    asm("v_cvt_pk_bf16_f32 %0, %1, %2" : "=v"(r) : "v"(a), "v"(b));
    return r;
}

__device__ __forceinline__ f32x4 bf4_to_f32(u16x4 v) {
    f32x4 r;
    r[0] = __uint_as_float((uint32_t)v[0] << 16);
    r[1] = __uint_as_float((uint32_t)v[1] << 16);
    r[2] = __uint_as_float((uint32_t)v[2] << 16);
    r[3] = __uint_as_float((uint32_t)v[3] << 16);
    return r;
}

// ---- FUSED: gemm1 (blocks [0,782)) + deg/pos (blocks [782,2345)) --------------
// gemm1: H = relu(X @ W1^T), fp32 inputs converted in-staging via cvtpk (the
// pattern gemm2's B-staging has used since r8). deg: memory-side-atomic-bound
// (74us floor, r9-r14). Co-residency overlaps MFMA with atomics.
// ALL buffers disjoint (r15 crash: deg/pos aliased the live Xb region).
__launch_bounds__(256)
__global__ void g1deg_k(const float* __restrict__ X, const float* __restrict__ W1,
                        ushort* __restrict__ H, const int* __restrict__ dst,
                        int* __restrict__ deg, int* __restrict__ pos) {
    __shared__ ushort sA[128 * 64];
    __shared__ ushort sB[128 * 64];
    const int bid = blockIdx.x;
    const int t = threadIdx.x;

    if (bid >= G1_BLOCKS) {
        // ---------------- degree + position branch -----------------------
        int e = ((bid - G1_BLOCKS) * 256 + t) * 4;
        if (e + 3 < N_EDGES) {
            const i32x4 d = __builtin_nontemporal_load(
                reinterpret_cast<const i32x4*>(dst + e));
            i32x4 p;
            p[0] = atomicAdd(&deg[d[0]], 1);
            p[1] = atomicAdd(&deg[d[1]], 1);
            p[2] = atomicAdd(&deg[d[2]], 1);
            p[3] = atomicAdd(&deg[d[3]], 1);
            __builtin_nontemporal_store(p, reinterpret_cast<i32x4*>(pos + e));
        } else {
            for (int k = 0; k < 4 && e + k < N_EDGES; ++k)
                pos[e + k] = atomicAdd(&deg[dst[e + k]], 1);
        }
        return;
    }

    // ---------------- gemm1 branch ---------------------------------------
    const int m0 = (bid >> 1) * 128;
    const int n0 = (bid & 1) * 128;
    const int wid = t >> 6, lane = t & 63;
    const int wr = wid >> 1, wc = wid & 1;
    const int lo = lane & 15, hi = lane >> 4;

    f32x4 acc[4][4] = {};

    for (int kt = 0; kt < N_FEAT; kt += 64) {
        // stage A: X fp32 -> bf16 (cvtpk), 128 rows x 64 k
        #pragma unroll
        for (int p = 0; p < 8; ++p) {
            int idx = p * 256 + t;
            int row = idx >> 4, f4 = idx & 15;
            int grow = m0 + row; if (grow > N_NODES - 1) grow = N_NODES - 1;
            const float4 v = *reinterpret_cast<const float4*>(X + (size_t)grow * N_FEAT + kt + f4 * 4);
            uint2 h; h.x = cvtpk(v.x, v.y); h.y = cvtpk(v.z, v.w);
            int g = f4 >> 1;
            int off = row * 64 + ((g ^ (row & 7)) << 3) + ((f4 & 1) << 2);
            *reinterpret_cast<uint2*>(&sA[off]) = h;
        }
        // stage B: W1 rows n0..n0+127 (cvtpk)
        #pragma unroll
        for (int p = 0; p < 8; ++p) {
            int idx = p * 256 + t;
            int row = idx >> 4, f4 = idx & 15;
            const float4 v = *reinterpret_cast<const float4*>(W1 + (size_t)(n0 + row) * N_FEAT + kt + f4 * 4);
            uint2 h; h.x = cvtpk(v.x, v.y); h.y = cvtpk(v.z, v.w);
            int g = f4 >> 1;
            int off = row * 64 + ((g ^ (row & 7)) << 3) + ((f4 & 1) << 2);
            *reinterpret_cast<uint2*>(&sB[off]) = h;
        }
        __syncthreads();
        #pragma unroll
        for (int kk = 0; kk < 2; ++kk) {
            const int g = kk * 4 + hi;
            s16x8 a[4], b[4];
            #pragma unroll
            for (int i = 0; i < 4; ++i) {
                int row = wr * 64 + i * 16 + lo;
                a[i] = *reinterpret_cast<const s16x8*>(&sA[row * 64 + ((g ^ (row & 7)) << 3)]);
            }
            #pragma unroll
            for (int j = 0; j < 4; ++j) {
                int row = wc * 64 + j * 16 + lo;
                b[j] = *reinterpret_cast<const s16x8*>(&sB[row * 64 + ((g ^ (row & 7)) << 3)]);
            }
            #pragma unroll
            for (int i = 0; i < 4; ++i)
                #pragma unroll
                for (int j = 0; j < 4; ++j)
                    acc[i][j] = __builtin_amdgcn_mfma_f32_16x16x32_bf16(a[i], b[j], acc[i][j], 0, 0, 0);
        }
        __syncthreads();
    }
    #pragma unroll
    for (int i = 0; i < 4; ++i) {
        int rbase = m0 + wr * 64 + i * 16 + hi * 4;
        #pragma unroll
        for (int j = 0; j < 4; ++j) {
            int col = n0 + wc * 64 + j * 16 + lo;
            #pragma unroll
            for (int r = 0; r < 4; ++r) {
                int row = rbase + r;
                if (row < N_NODES) {
                    float v = acc[i][j][r];
                    H[(size_t)row * N_HID + col] = f2bf(fmaxf(v, 0.0f));
                }
            }
        }
    }
}

// ---- dinv/rd + scan partial (fused: both read deg[i]) -------------------------
__device__ __forceinline__ int wave_incl_scan(int v, int lane) {
    #pragma unroll
    for (int d = 1; d < 64; d <<= 1) {
        int u = __shfl_up(v, d, 64);
        if (lane >= d) v += u;
    }
    return v;
}

__global__ void dsc1_k(const int* __restrict__ deg, float* __restrict__ dinv,
                       float* __restrict__ rd, int* __restrict__ partial) {
    int i = blockIdx.x * 256 + threadIdx.x;
    int d = (i < N_NODES) ? deg[i] : 0;
    if (i < N_NODES) {
        float dp1 = (float)d + 1.0f;          // +1 self loop
        dinv[i] = rsqrtf(dp1);
        rd[i]   = sqrtf(dp1);
    }
    int v = (i < N_NODES) ? P16(d) : 0;
    #pragma unroll
    for (int s = 32; s; s >>= 1) v += __shfl_xor(v, s, 64);
    __shared__ int wt[4];
    int wid = threadIdx.x >> 6, lane = threadIdx.x & 63;
    if (lane == 0) wt[wid] = v;
    __syncthreads();
    if (threadIdx.x == 0) partial[blockIdx.x] = wt[0] + wt[1] + wt[2] + wt[3];
}

// ---- scan_p2 + zdum (single block; spare threads zero the dummy rows) ---------
__global__ void sc2_k(const int* __restrict__ partial, int* __restrict__ chunkoff,
                      int* __restrict__ row_ptr, ushort* __restrict__ b0,
                      ushort* __restrict__ b1, ushort* __restrict__ b2) {
    int t = threadIdx.x;
    int v = (t < 196) ? partial[t] : 0;
    int lane = t & 63, wid = t >> 6;
    int incl = wave_incl_scan(v, lane);
    __shared__ int wt[4];
    if (lane == 63) wt[wid] = incl;
    __syncthreads();
    int woff = 0;
    for (int w = 0; w < wid; ++w) woff += wt[w];
    int excl = incl - v + woff;
    if (t < 196) chunkoff[t] = excl;
    if (t == 0) row_ptr[N_NODES] = wt[0] + wt[1] + wt[2] + wt[3];  // padded total
    // zero the dummy row (64 bf16) in the 3 state buffers
    if (t < 192) {
        ushort* b = (t < 64) ? b0 : (t < 128) ? b1 : b2;
        b[(size_t)DUMMY * 64 + (t & 63)] = 0;
    }
}

// ---- scan_p3 + padfill (row_ptr[i] is local; pad [deg, P16) with DUMMY) -------
__global__ void sc3_k(const int* __restrict__ cnt, const int* __restrict__ chunkoff,
                      int* __restrict__ row_ptr, int* __restrict__ csr) {
    int i = blockIdx.x * 256 + threadIdx.x;
    int dg = (i < N_NODES) ? cnt[i] : 0;
    int v = (i < N_NODES) ? P16(dg) : 0;
    int lane = threadIdx.x & 63, wid = threadIdx.x >> 6;
    int incl = wave_incl_scan(v, lane);
    __shared__ int wt[4];
    if (lane == 63) wt[wid] = incl;
    __syncthreads();
    int woff = 0;
    for (int w = 0; w < wid; ++w) woff += wt[w];
    int excl = incl - v + woff;
    if (i < N_NODES) {
        int rp = chunkoff[blockIdx.x] + excl;
        row_ptr[i] = rp;
        int base = rp + dg;
        int pad = P16(dg) - dg;
        for (int k = 0; k < pad; ++k) csr[base + k] = DUMMY;
    }
}

// ---- FUSED: gemm2 (blocks [0,391)) + atomic-free scatter ([391,1954)) ---------
__launch_bounds__(256)
__global__ void scg2_k(const ushort* __restrict__ H, const float* __restrict__ W2,
                       const float* __restrict__ dinv, ushort* __restrict__ out,
                       const int* __restrict__ src, const int* __restrict__ dst,
                       const int* __restrict__ pos, const int* __restrict__ row_ptr,
                       int* __restrict__ csr) {
    __shared__ ushort sA[128 * 64];
    __shared__ ushort sB[64 * 64];
    const int bid = blockIdx.x;
    const int t = threadIdx.x;

    if (bid >= G2_BLOCKS) {
        // ---------------- scatter branch (atomic-free) --------------------
        int e = ((bid - G2_BLOCKS) * 256 + t) * 4;
        if (e + 3 < N_EDGES) {
            const i32x4 d4 = __builtin_nontemporal_load(
                reinterpret_cast<const i32x4*>(dst + e));
            const i32x4 s4 = __builtin_nontemporal_load(
                reinterpret_cast<const i32x4*>(src + e));
            const i32x4 p4 = __builtin_nontemporal_load(
                reinterpret_cast<const i32x4*>(pos + e));
            #pragma unroll
            for (int k = 0; k < 4; ++k)
                csr[row_ptr[d4[k]] + p4[k]] = s4[k];
        } else {
            for (int k = 0; k < 4 && e + k < N_EDGES; ++k)
                csr[row_ptr[dst[e + k]] + pos[e + k]] = src[e + k];
        }
        return;
    }

    // ---------------- gemm2 branch ----------------------------------------
    const int m0 = bid * 128;
    const int wid = t >> 6, lane = t & 63;
    const int lo = lane & 15, hi = lane >> 4;

    f32x4 acc[2][4] = {};

    for (int kt = 0; kt < N_HID; kt += 64) {
        #pragma unroll
        for (int p = 0; p < 4; ++p) {
            int idx = p * 256 + t;
            int row = idx >> 3, g = idx & 7;
            int grow = m0 + row; if (grow > N_NODES - 1) grow = N_NODES - 1;
            uint4 v = *reinterpret_cast<const uint4*>(H + (size_t)grow * N_HID + kt + g * 8);
            *reinterpret_cast<uint4*>(&sA[row * 64 + ((g ^ (row & 7)) << 3)]) = v;
        }
        #pragma unroll
        for (int p = 0; p < 4; ++p) {
            int idx = p * 256 + t;
            int row = idx >> 4, f4 = idx & 15;
            const float4 v = *reinterpret_cast<const float4*>(W2 + (size_t)row * N_HID + kt + f4 * 4);
            uint2 h; h.x = cvtpk(v.x, v.y); h.y = cvtpk(v.z, v.w);
            int g = f4 >> 1;
            int off = row * 64 + ((g ^ (row & 7)) << 3) + ((f4 & 1) << 2);
            *reinterpret_cast<uint2*>(&sB[off]) = h;
        }
        __syncthreads();
        #pragma unroll
        for (int kk = 0; kk < 2; ++kk) {
            const int g = kk * 4 + hi;
            s16x8 a[2], b[4];
            #pragma unroll
            for (int i = 0; i < 2; ++i) {
                int row = wid * 32 + i * 16 + lo;
                a[i] = *reinterpret_cast<const s16x8*>(&sA[row * 64 + ((g ^ (row & 7)) << 3)]);
            }
            #pragma unroll
            for (int j = 0; j < 4; ++j) {
                int row = j * 16 + lo;
                b[j] = *reinterpret_cast<const s16x8*>(&sB[row * 64 + ((g ^ (row & 7)) << 3)]);
            }
            #pragma unroll
            for (int i = 0; i < 2; ++i)
                #pragma unroll
                for (int j = 0; j < 4; ++j)
                    acc[i][j] = __builtin_amdgcn_mfma_f32_16x16x32_bf16(a[i], b[j], acc[i][j], 0, 0, 0);
        }
        __syncthreads();
    }
    // row-major bf16 store scaled by dinv: out[row][j*16+lo]
    #pragma unroll
    for (int i = 0; i < 2; ++i) {
        int rbase = m0 + wid * 32 + i * 16 + hi * 4;
        #pragma unroll
        for (int r = 0; r < 4; ++r) {
            int row = rbase + r;
            if (row < N_NODES) {
                const float dv = dinv[row];
                #pragma unroll
                for (int j = 0; j < 4; ++j)
                    out[(size_t)row * 64 + j * 16 + lo] = f2bf(acc[i][j][r] * dv);
            }
        }
    }
}

// ---------------- one APPNP hop: single-pass full-row, BF16 planes -------------
// p~'[d] = 0.9*dinv[d]^2*(sum_{s in N(d)} p~[s] + p~[d]) + 0.1*h~0[d]
// Planes row-major [NPAD][64] bf16 (128B rows, 6.4MB/plane; fp32 accum).
// Wave = 4 edge-slots x 16 lanes x u16x4 (8B). 32-entry main loop = 8 gathers
// in flight/lane; 16-entry tail (P16 segments). 4 nodes/wave, csr LDS-staged.
__launch_bounds__(256)
__global__ void hop_k(const ushort* __restrict__ prev, const ushort* __restrict__ h0,
                      ushort* __restrict__ next, const int* __restrict__ csr,
                      const int* __restrict__ row_ptr, const float* __restrict__ dinv) {
    __shared__ int scsr[4][STAGE_CAP];
    const int bid = blockIdx.x;
    const int wid = threadIdx.x >> 6;
    const int lane = threadIdx.x & 63;
    const int nb = bid * 16 + wid * 4;             // first of this wave's 4 nodes
    const int slot = lane >> 4;                    // edge slot 0..3
    const int cq = (lane & 15) << 2;               // bf16 offset in 64-elem row

    const int b0 = __builtin_amdgcn_readfirstlane(row_ptr[nb]);
    const int e0 = __builtin_amdgcn_readfirstlane(row_ptr[nb + 1]);
    const int e1 = __builtin_amdgcn_readfirstlane(row_ptr[nb + 2]);
    const int e2 = __builtin_amdgcn_readfirstlane(row_ptr[nb + 3]);
    const int e3 = __builtin_amdgcn_readfirstlane(row_ptr[nb + 4]);
    const int tot = e3 - b0;

    int* sw = scsr[wid];
    #pragma unroll
    for (int k = 0; k < 4; ++k) {
        int off = k * 64 + lane;
        if (off < tot && off < STAGE_CAP)
            sw[off] = __builtin_nontemporal_load(csr + b0 + off);
    }

    f32x4 a0 = {0.f,0.f,0.f,0.f}, a1 = a0, a2 = a0, a3 = a0;

#define NODE_LOOP(Bg, Eg, ACC)                                                   \
    {                                                                            \
        int ib = (Bg);                                                           \
        for (; ib + 32 <= (Eg); ib += 32) {                                      \
            int s[8];                                                            \
            if (ib + 32 - b0 <= STAGE_CAP) {                                     \
                int base = ib - b0 + slot;                                       \
                _Pragma("unroll")                                                \
                for (int k = 0; k < 8; ++k) s[k] = sw[base + 4 * k];             \
            } else {                                                             \
                _Pragma("unroll")                                                \
                for (int k = 0; k < 8; ++k)                                      \
                    s[k] = __builtin_nontemporal_load(csr + ib + slot + 4 * k);  \
            }                                                                    \
            u16x4 p[8];                                                          \
            _Pragma("unroll")                                                    \
            for (int k = 0; k < 8; ++k)                                          \
                p[k] = *reinterpret_cast<const u16x4*>(prev + (size_t)s[k] * 64 + cq); \
            _Pragma("unroll")                                                    \
            for (int k = 0; k < 8; ++k) {                                        \
                const f32x4 f = bf4_to_f32(p[k]);                                \
                ACC[0] += f[0]; ACC[1] += f[1]; ACC[2] += f[2]; ACC[3] += f[3];  \
            }                                                                    \
        }                                                                        \
        if (ib < (Eg)) {                                                         \
            int s[4];                                                            \
            if (ib + 16 - b0 <= STAGE_CAP) {                                     \
                int base = ib - b0 + slot;                                       \
                _Pragma("unroll")                                                \
                for (int k = 0; k < 4; ++k) s[k] = sw[base + 4 * k];             \
            } else {                                                             \
                _Pragma("unroll")                                                \
                for (int k = 0; k < 4; ++k)                                      \
                    s[k] = __builtin_nontemporal_load(csr + ib + slot + 4 * k);  \
            }                                                                    \
            u16x4 p[4];                                                          \
            _Pragma("unroll")                                                    \
            for (int k = 0; k < 4; ++k)                                          \
                p[k] = *reinterpret_cast<const u16x4*>(prev + (size_t)s[k] * 64 + cq); \
            _Pragma("unroll")                                                    \
            for (int k = 0; k < 4; ++k) {                                        \
                const f32x4 f = bf4_to_f32(p[k]);                                \
                ACC[0] += f[0]; ACC[1] += f[1]; ACC[2] += f[2]; ACC[3] += f[3];  \
            }                                                                    \
        }                                                                        \
    }

    NODE_LOOP(b0, e0, a0)
    NODE_LOOP(e0, e1, a1)
    NODE_LOOP(e1, e2, a2)
    NODE_LOOP(e2, e3, a3)
#undef NODE_LOOP

    #pragma unroll
    for (int c = 0; c < 4; ++c) {
        a0[c] += __shfl_xor(a0[c], 16, 64); a0[c] += __shfl_xor(a0[c], 32, 64);
        a1[c] += __shfl_xor(a1[c], 16, 64); a1[c] += __shfl_xor(a1[c], 32, 64);
        a2[c] += __shfl_xor(a2[c], 16, 64); a2[c] += __shfl_xor(a2[c], 32, 64);
        a3[c] += __shfl_xor(a3[c], 16, 64); a3[c] += __shfl_xor(a3[c], 32, 64);
    }

    {
        const int node = nb + slot;
        const float di = dinv[node];
        const float di2 = di * di;
        f32x4 av = a0;
        if (slot == 1) av = a1;
        if (slot == 2) av = a2;
        if (slot == 3) av = a3;
        const size_t off = (size_t)node * 64 + cq;
        const f32x4 pv = bf4_to_f32(*reinterpret_cast<const u16x4*>(prev + off));
        const f32x4 hh = bf4_to_f32(__builtin_nontemporal_load(
            reinterpret_cast<const u16x4*>(h0 + off)));
        float r0 = 0.9f * di2 * (av[0] + pv[0]) + 0.1f * hh[0];
        float r1 = 0.9f * di2 * (av[1] + pv[1]) + 0.1f * hh[1];
        float r2 = 0.9f * di2 * (av[2] + pv[2]) + 0.1f * hh[2];
        float r3 = 0.9f * di2 * (av[3] + pv[3]) + 0.1f * hh[3];
        u32x2 o;
        o[0] = cvtpk(r0, r1);
        o[1] = cvtpk(r2, r3);
        __builtin_nontemporal_store(o, reinterpret_cast<u32x2*>(next + off));
    }
}

// ---- log_softmax over 64 classes; bf16 scaled planes, rescale by rd -----------
__launch_bounds__(256)
__global__ void logsm_k(const ushort* __restrict__ in, const float* __restrict__ rd,
                        float* __restrict__ out) {
    int r = (blockIdx.x * 256 + threadIdx.x) >> 6;
    int lane = threadIdx.x & 63;
    if (r >= N_NODES) return;
    float v = __uint_as_float((uint32_t)in[(size_t)r * 64 + lane] << 16) * rd[r];
    float m = v;
    #pragma unroll
    for (int d = 32; d; d >>= 1) m = fmaxf(m, __shfl_xor(m, d, 64));
    float e = __expf(v - m);
    float s = e;
    #pragma unroll
    for (int d = 32; d; d >>= 1) s += __shfl_xor(s, d, 64);
    out[(size_t)r * N_CLS + lane] = (v - m) - __logf(s);
}

extern "C" void kernel_launch(void* const* d_in, const int* in_sizes, int n_in,
                              void* d_out, int out_size, void* d_ws, size_t ws_size,
                              hipStream_t stream) {
    const float* X  = (const float*)d_in[0];
    const int*   EI = (const int*)d_in[1];
    const float* W1 = (const float*)d_in[2];
    const float* W2 = (const float*)d_in[3];
    const int* src = EI;
    const int* dst = EI + N_EDGES;

    char* ws = (char*)d_ws;
    // ALL buffers disjoint (total 61.6MB < proven-safe 77.6MB). No aliasing.
    ushort* H      = (ushort*)(ws + 0);                 // 25,600,000 B
    int*    csr    = (int*)  (ws + 25600000);           //  9,600,000 B
    int*    deg    = (int*)  (ws + 35200000);           //    200,000 B
    float*  dinv   = (float*)(ws + 35400000);           //    200,000 B
    float*  rd     = (float*)(ws + 35600000);           //    200,000 B
    int*    rptr   = (int*)  (ws + 35800000);           //    200,004 B
    int*    part   = (int*)  (ws + 36000016);           //        784 B
    int*    coff   = (int*)  (ws + 36001024);           //        784 B
    int*    pos    = (int*)  (ws + 36002048);           //  6,400,000 B
    ushort* h0t    = (ushort*)(ws + 42402048);          //  6,402,048 B [NPAD][64]
    ushort* pp0    = (ushort*)(ws + 48804096);          //  6,402,048 B
    ushort* pp1    = (ushort*)(ws + 55206144);          //  6,402,048 B (ends 61.6MB)

    hipMemsetAsync(deg, 0, N_NODES * sizeof(int), stream);

    // 1) FUSED gemm1 (fp32-in, cvtpk staging) + deg/pos (MFMA || atomics)
    g1deg_k<<<G1_BLOCKS + DEG_BLOCKS, 256, 0, stream>>>(X, W1, H, dst, deg, pos);

    // 2) dinv/rd + scan (fused small kernels)
    dsc1_k<<<196, 256, 0, stream>>>(deg, dinv, rd, part);
    sc2_k<<<1, 256, 0, stream>>>(part, coff, rptr, h0t, pp0, pp1);
    sc3_k<<<196, 256, 0, stream>>>(deg, coff, rptr, csr);

    // 3) FUSED gemm2 + atomic-free scatter (MFMA || streaming)
    scg2_k<<<G2_BLOCKS + SCAT_BLOCKS, 256, 0, stream>>>(H, W2, dinv, h0t,
                                                        src, dst, pos, rptr, csr);

    const ushort* p = h0t;
    ushort* bufs[2] = {pp0, pp1};
    for (int k = 0; k < K_HOPS; ++k) {
        ushort* nx = bufs[k & 1];
        hop_k<<<HOP_GRID, 256, 0, stream>>>(p, h0t, nx, csr, rptr, dinv);
        p = nx;
    }
    logsm_k<<<12500, 256, 0, stream>>>(p, rd, (float*)d_out);
}